// Round 1
// baseline (2909.688 us; speedup 1.0000x reference)
//
#include <hip/hip_runtime.h>
#include <math.h>

#define N_NODES 50000
#define E_EDGES 800000
#define FDIM_IN 128
#define HID_1 32
#define HEADS_1 8
#define H1DIM 256
#define NUM_WALKS 512
#define WALK_LEN 64
#define WINDOW 5
#define NEG_S 10
#define TEMP 0.07f
#define NEG_SLOPE 0.2f
#define TOT_EDGES (E_EDGES + N_NODES)

__device__ __forceinline__ void atomicMaxFloat(float* addr, float val) {
    // monotonic int-punning trick; works with -inf init
    if (val >= 0.f) {
        atomicMax((int*)addr, __float_as_int(val));
    } else {
        atomicMin((unsigned int*)addr, (unsigned int)__float_as_int(val));
    }
}

__global__ void fill_kernel(float* __restrict__ p, float v, int n) {
    int i = blockIdx.x * blockDim.x + threadIdx.x;
    if (i < n) p[i] = v;
}

// Y[n][j] = sum_k X[n][k] * W[k][j], 256 output cols, 16 rows per block
template<int K>
__global__ __launch_bounds__(256) void gemm_rows(const float* __restrict__ X,
                                                 const float* __restrict__ W,
                                                 float* __restrict__ Y) {
    __shared__ float xs[16][K];
    const int row0 = blockIdx.x * 16;
    const int t = threadIdx.x;
    for (int i = t; i < 16 * K; i += 256) {
        int r = i / K, k = i % K;
        xs[r][k] = X[(size_t)(row0 + r) * K + k];
    }
    __syncthreads();
    float acc[16];
#pragma unroll
    for (int r = 0; r < 16; r++) acc[r] = 0.f;
    for (int k = 0; k < K; k++) {
        float w = W[k * 256 + t];
#pragma unroll
        for (int r = 0; r < 16; r++) acc[r] += xs[r][k] * w;
    }
#pragma unroll
    for (int r = 0; r < 16; r++) Y[(size_t)(row0 + r) * 256 + t] = acc[r];
}

// al_s[n][h] = sum_c xw[n][h*hid+c]*a_src[h][c]; same for al_d
__global__ void al_kernel(const float* __restrict__ xw,
                          const float* __restrict__ a_src, const float* __restrict__ a_dst,
                          float* __restrict__ als, float* __restrict__ ald,
                          int heads, int hid) {
    int i = blockIdx.x * blockDim.x + threadIdx.x;
    if (i >= N_NODES * heads) return;
    int n = i / heads, h = i % heads;
    const float* row = xw + (size_t)n * 256 + h * hid;
    const float* as = a_src + h * hid;
    const float* ad = a_dst + h * hid;
    float s = 0.f, d = 0.f;
    for (int c = 0; c < hid; c++) {
        float v = row[c];
        s += v * as[c];
        d += v * ad[c];
    }
    als[i] = s;
    ald[i] = d;
}

__global__ void edge_max_kernel(const int* __restrict__ ei,
                                const float* __restrict__ als, const float* __restrict__ ald,
                                float* __restrict__ m, int heads) {
    int e = blockIdx.x * blockDim.x + threadIdx.x;
    if (e >= TOT_EDGES) return;
    int src, dst;
    if (e < E_EDGES) { src = ei[e]; dst = ei[E_EDGES + e]; }
    else             { src = dst = e - E_EDGES; }
    for (int h = 0; h < heads; h++) {
        float v = als[src * heads + h] + ald[dst * heads + h];
        v = v > 0.f ? v : v * NEG_SLOPE;
        atomicMaxFloat(&m[dst * heads + h], v);
    }
}

// one block (256 thr) per edge: acc[dst][t] += ex[h]*xw[src][t]; den[dst][h] += ex[h]
__global__ __launch_bounds__(256) void edge_scatter_kernel(
        const int* __restrict__ ei,
        const float* __restrict__ als, const float* __restrict__ ald,
        const float* __restrict__ m, const float* __restrict__ xw,
        float* __restrict__ den, float* __restrict__ acc, int heads) {
    int e = blockIdx.x;
    int t = threadIdx.x;
    int src, dst;
    if (e < E_EDGES) { src = ei[e]; dst = ei[E_EDGES + e]; }
    else             { src = dst = e - E_EDGES; }
    int hid = 256 / heads;
    int h = t / hid;
    float v = als[src * heads + h] + ald[dst * heads + h];
    v = v > 0.f ? v : v * NEG_SLOPE;
    float ex = expf(v - m[dst * heads + h]);
    if ((t & (hid - 1)) == 0) atomicAdd(&den[dst * heads + h], ex);
    atomicAdd(&acc[(size_t)dst * 256 + t], ex * xw[(size_t)src * 256 + t]);
}

__global__ void norm1_kernel(float* __restrict__ acc, const float* __restrict__ den,
                             const float* __restrict__ b) {
    int n = blockIdx.x, t = threadIdx.x;
    float v = acc[(size_t)n * 256 + t] / den[n * HEADS_1 + (t >> 5)] + b[t];
    v = v > 0.f ? v : (expf(v) - 1.f);  // elu
    acc[(size_t)n * 256 + t] = v;
}

__global__ void norm2_kernel(float* __restrict__ acc, const float* __restrict__ den,
                             const float* __restrict__ b) {
    int n = blockIdx.x, t = threadIdx.x;
    acc[(size_t)n * 256 + t] = acc[(size_t)n * 256 + t] / den[n] + b[t];
}

__global__ void inv_norm_kernel(const float* __restrict__ emb1, const float* __restrict__ emb2,
                                float* __restrict__ invn) {
    int n = blockIdx.x, t = threadIdx.x;
    float v1 = emb1[(size_t)n * 256 + t];
    float v2 = emb2[(size_t)n * 256 + t];
    float s = v1 * v1 + v2 * v2;
    __shared__ float red[4];
    for (int o = 32; o > 0; o >>= 1) s += __shfl_xor(s, o, 64);
    if ((t & 63) == 0) red[t >> 6] = s;
    __syncthreads();
    if (t == 0) {
        float tot = red[0] + red[1] + red[2] + red[3];
        invn[n] = 1.f / fmaxf(sqrtf(tot), 1e-8f);
    }
}

__global__ __launch_bounds__(256) void loss_kernel(
        const float* __restrict__ emb1, const float* __restrict__ emb2,
        const float* __restrict__ invn,
        const int* __restrict__ walks, const int* __restrict__ negs,
        float* __restrict__ out) {
    __shared__ float anchor[512];
    __shared__ int pos_id[2 * WINDOW];
    __shared__ int pos_valid[2 * WINDOW];
    __shared__ float s_pos, s_neg;
    const int bl = blockIdx.x;
    const int b = bl / WALK_LEN, l = bl % WALK_LEN;
    const int t = threadIdx.x;
    if (t == 0) { s_pos = 0.f; s_neg = 0.f; }
    const int an = walks[b * WALK_LEN + l];
    const float inv_a = invn[an];
    for (int d = t; d < 512; d += 256) {
        float v = (d < 256) ? emb1[(size_t)an * 256 + d] : emb2[(size_t)an * 256 + (d - 256)];
        anchor[d] = v * inv_a;
    }
    if (t < 2 * WINDOW) {
        int off = (t < WINDOW) ? (t - WINDOW) : (t - WINDOW + 1);
        int pp = l + off;
        int valid = (pp >= 0 && pp < WALK_LEN) ? 1 : 0;
        int ppc = min(max(pp, 0), WALK_LEN - 1);
        pos_id[t] = walks[b * WALK_LEN + ppc];
        pos_valid[t] = valid;
    }
    __syncthreads();
    const int wave = t >> 6, lane = t & 63;
    for (int cand = wave; cand < 2 * WINDOW + NEG_S; cand += 4) {
        int node;
        if (cand < 2 * WINDOW) {
            if (!pos_valid[cand]) continue;
            node = pos_id[cand];
        } else {
            int s = cand - 2 * WINDOW;
            node = negs[(size_t)(b * WALK_LEN + l) * NEG_S + s];
            bool masked = false;
#pragma unroll
            for (int p = 0; p < 2 * WINDOW; p++)
                masked = masked || (pos_valid[p] && pos_id[p] == node);
            if (masked) continue;
        }
        const float ninv = invn[node];
        float part = 0.f;
        for (int d = lane; d < 512; d += 64) {
            float v = (d < 256) ? emb1[(size_t)node * 256 + d] : emb2[(size_t)node * 256 + (d - 256)];
            part += anchor[d] * v;
        }
        part *= ninv;
        for (int o = 32; o > 0; o >>= 1) part += __shfl_xor(part, o, 64);
        if (lane == 0) {
            float eres = expf(part / TEMP);
            if (cand < 2 * WINDOW) atomicAdd(&s_pos, eres);
            else                   atomicAdd(&s_neg, eres);
        }
    }
    __syncthreads();
    if (t == 0) {
        float term = (s_pos > 0.f) ? logf(1.f + s_neg / s_pos) : 0.f;
        atomicAdd(out, term);
    }
}

extern "C" void kernel_launch(void* const* d_in, const int* in_sizes, int n_in,
                              void* d_out, int out_size, void* d_ws, size_t ws_size,
                              hipStream_t stream) {
    const float* x      = (const float*)d_in[0];
    const int*   ei     = (const int*)d_in[1];
    const int*   walks  = (const int*)d_in[2];
    const int*   negs   = (const int*)d_in[3];
    const float* W1     = (const float*)d_in[4];
    const float* a_src1 = (const float*)d_in[5];
    const float* a_dst1 = (const float*)d_in[6];
    const float* b1     = (const float*)d_in[7];
    const float* W2     = (const float*)d_in[8];
    const float* a_src2 = (const float*)d_in[9];
    const float* a_dst2 = (const float*)d_in[10];
    const float* b2     = (const float*)d_in[11];
    float* out = (float*)d_out;

    float* ws = (float*)d_ws;
    size_t off = 0;
    float* xw   = ws + off; off += (size_t)N_NODES * 256;   // layer1 xw, reused as layer2 xw
    float* acc1 = ws + off; off += (size_t)N_NODES * 256;   // becomes emb1
    float* acc2 = ws + off; off += (size_t)N_NODES * 256;   // becomes emb2
    float* als1 = ws + off; off += N_NODES * HEADS_1;
    float* ald1 = ws + off; off += N_NODES * HEADS_1;
    float* m1   = ws + off; off += N_NODES * HEADS_1;
    float* den1 = ws + off; off += N_NODES * HEADS_1;
    float* als2 = ws + off; off += N_NODES;
    float* ald2 = ws + off; off += N_NODES;
    float* m2   = ws + off; off += N_NODES;
    float* den2 = ws + off; off += N_NODES;
    float* invn = ws + off; off += N_NODES;

    hipMemsetAsync(out, 0, sizeof(float) * out_size, stream);
    hipMemsetAsync(acc1, 0, sizeof(float) * (size_t)N_NODES * 256, stream);
    hipMemsetAsync(acc2, 0, sizeof(float) * (size_t)N_NODES * 256, stream);
    hipMemsetAsync(den1, 0, sizeof(float) * N_NODES * HEADS_1, stream);
    hipMemsetAsync(den2, 0, sizeof(float) * N_NODES, stream);
    fill_kernel<<<(N_NODES * HEADS_1 + 255) / 256, 256, 0, stream>>>(m1, -INFINITY, N_NODES * HEADS_1);
    fill_kernel<<<(N_NODES + 255) / 256, 256, 0, stream>>>(m2, -INFINITY, N_NODES);

    // ---- layer 1 (heads=8, hid=32) ----
    gemm_rows<128><<<N_NODES / 16, 256, 0, stream>>>(x, W1, xw);
    al_kernel<<<(N_NODES * HEADS_1 + 255) / 256, 256, 0, stream>>>(xw, a_src1, a_dst1, als1, ald1, HEADS_1, HID_1);
    edge_max_kernel<<<(TOT_EDGES + 255) / 256, 256, 0, stream>>>(ei, als1, ald1, m1, HEADS_1);
    edge_scatter_kernel<<<TOT_EDGES, 256, 0, stream>>>(ei, als1, ald1, m1, xw, den1, acc1, HEADS_1);
    norm1_kernel<<<N_NODES, 256, 0, stream>>>(acc1, den1, b1);   // acc1 -> emb1 (elu)

    // ---- layer 2 (heads=1, hid=256) ----
    gemm_rows<256><<<N_NODES / 16, 256, 0, stream>>>(acc1, W2, xw);
    al_kernel<<<(N_NODES + 255) / 256, 256, 0, stream>>>(xw, a_src2, a_dst2, als2, ald2, 1, H1DIM);
    edge_max_kernel<<<(TOT_EDGES + 255) / 256, 256, 0, stream>>>(ei, als2, ald2, m2, 1);
    edge_scatter_kernel<<<TOT_EDGES, 256, 0, stream>>>(ei, als2, ald2, m2, xw, den2, acc2, 1);
    norm2_kernel<<<N_NODES, 256, 0, stream>>>(acc2, den2, b2);   // acc2 -> emb2

    // ---- contrastive loss ----
    inv_norm_kernel<<<N_NODES, 256, 0, stream>>>(acc1, acc2, invn);
    loss_kernel<<<NUM_WALKS * WALK_LEN, 256, 0, stream>>>(acc1, acc2, invn, walks, negs, out);
}

// Round 2
// 1530.591 us; speedup vs baseline: 1.9010x; 1.9010x over previous
//
#include <hip/hip_runtime.h>
#include <math.h>

#define N_NODES 50000
#define E_EDGES 800000
#define FDIM_IN 128
#define HID_1 32
#define HEADS_1 8
#define H1DIM 256
#define NUM_WALKS 512
#define WALK_LEN 64
#define WINDOW 5
#define NEG_S 10
#define TEMP 0.07f
#define NEG_SLOPE 0.2f

#define SCAN_BLOCKS ((N_NODES + 255) / 256)   // 196

__device__ __forceinline__ float leaky(float v) {
    return v > 0.f ? v : v * NEG_SLOPE;
}

// ---------------- CSR build ----------------

__global__ void deg_kernel(const int* __restrict__ ei, int* __restrict__ deg) {
    int e = blockIdx.x * blockDim.x + threadIdx.x;
    if (e < E_EDGES) atomicAdd(&deg[ei[E_EDGES + e]], 1);
}

// per-block exclusive scan + block sums
__global__ __launch_bounds__(256) void scan_a(const int* __restrict__ deg,
                                              int* __restrict__ excl,
                                              int* __restrict__ bsum) {
    __shared__ int s[256];
    int t = threadIdx.x;
    int i = blockIdx.x * 256 + t;
    int v = (i < N_NODES) ? deg[i] : 0;
    s[t] = v;
    __syncthreads();
    for (int off = 1; off < 256; off <<= 1) {
        int tmp = (t >= off) ? s[t - off] : 0;
        __syncthreads();
        s[t] += tmp;
        __syncthreads();
    }
    if (i < N_NODES) excl[i] = s[t] - v;
    if (t == 255) bsum[blockIdx.x] = s[255];
}

__global__ __launch_bounds__(256) void scan_b(int* __restrict__ bsum) {
    __shared__ int s[256];
    int t = threadIdx.x;
    int v = (t < SCAN_BLOCKS) ? bsum[t] : 0;
    s[t] = v;
    __syncthreads();
    for (int off = 1; off < 256; off <<= 1) {
        int tmp = (t >= off) ? s[t - off] : 0;
        __syncthreads();
        s[t] += tmp;
        __syncthreads();
    }
    if (t < SCAN_BLOCKS) bsum[t] = s[t] - v;   // exclusive
}

__global__ void scan_c(int* __restrict__ excl, const int* __restrict__ bsum,
                       int* __restrict__ row_start) {
    int i = blockIdx.x * blockDim.x + threadIdx.x;
    if (i < N_NODES) row_start[i] = excl[i] + bsum[blockIdx.x * blockDim.x / 256 + (threadIdx.x + blockIdx.x * blockDim.x) / 256 - i / 256 + i / 256];  // placeholder avoided below
}

// simpler correct version (used): i/256 indexes bsum
__global__ void scan_c2(int* __restrict__ excl, const int* __restrict__ bsum,
                        int* __restrict__ row_start) {
    int i = blockIdx.x * blockDim.x + threadIdx.x;
    if (i < N_NODES) row_start[i] = excl[i] + bsum[i >> 8];
    if (i == 0) row_start[N_NODES] = E_EDGES;
}

__global__ void bucket_kernel(const int* __restrict__ ei,
                              const int* __restrict__ row_start,
                              int* __restrict__ cursor,
                              int* __restrict__ srclist) {
    int e = blockIdx.x * blockDim.x + threadIdx.x;
    if (e >= E_EDGES) return;
    int dst = ei[E_EDGES + e];
    int pos = atomicAdd(&cursor[dst], 1);
    srclist[row_start[dst] + pos] = ei[e];
}

// ---------------- dense compute ----------------

// Y[n][j] = sum_k X[n][k] * W[k][j], 256 output cols, 16 rows per block
template<int K>
__global__ __launch_bounds__(256) void gemm_rows(const float* __restrict__ X,
                                                 const float* __restrict__ W,
                                                 float* __restrict__ Y) {
    __shared__ float xs[16][K];
    const int row0 = blockIdx.x * 16;
    const int t = threadIdx.x;
    for (int i = t; i < 16 * K; i += 256) {
        int r = i / K, k = i % K;
        xs[r][k] = X[(size_t)(row0 + r) * K + k];
    }
    __syncthreads();
    float acc[16];
#pragma unroll
    for (int r = 0; r < 16; r++) acc[r] = 0.f;
    for (int k = 0; k < K; k++) {
        float w = W[k * 256 + t];
#pragma unroll
        for (int r = 0; r < 16; r++) acc[r] += xs[r][k] * w;
    }
#pragma unroll
    for (int r = 0; r < 16; r++) Y[(size_t)(row0 + r) * 256 + t] = acc[r];
}

__global__ void al_kernel(const float* __restrict__ xw,
                          const float* __restrict__ a_src, const float* __restrict__ a_dst,
                          float* __restrict__ als, float* __restrict__ ald,
                          int heads, int hid) {
    int i = blockIdx.x * blockDim.x + threadIdx.x;
    if (i >= N_NODES * heads) return;
    int n = i / heads, h = i % heads;
    const float* row = xw + (size_t)n * 256 + h * hid;
    const float* as = a_src + h * hid;
    const float* ad = a_dst + h * hid;
    float s = 0.f, d = 0.f;
    for (int c = 0; c < hid; c++) {
        float v = row[c];
        s += v * as[c];
        d += v * ad[c];
    }
    als[i] = s;
    ald[i] = d;
}

// one block per dst node: max -> exp/den/acc -> normalize+bias(+elu), no atomics
template<int H, bool DO_ELU>
__global__ __launch_bounds__(256) void gat_gather(
        const int* __restrict__ row_start, const int* __restrict__ srclist,
        const float* __restrict__ als, const float* __restrict__ ald,
        const float* __restrict__ xw, const float* __restrict__ bias,
        float* __restrict__ outbuf) {
    const int n = blockIdx.x;
    const int t = threadIdx.x;
    const int h = t / (256 / H);
    const float ald_n = ald[n * H + h];
    const float self_v = leaky(als[n * H + h] + ald_n);
    const int beg = row_start[n], end = row_start[n + 1];

    float mx = self_v;
    for (int i = beg; i < end; i++) {
        int s = srclist[i];
        mx = fmaxf(mx, leaky(als[s * H + h] + ald_n));
    }

    float den, acc;
    {
        float ex = expf(self_v - mx);
        den = ex;
        acc = ex * xw[(size_t)n * 256 + t];
    }
    for (int i = beg; i < end; i++) {
        int s = srclist[i];
        float ex = expf(leaky(als[s * H + h] + ald_n) - mx);
        den += ex;
        acc += ex * xw[(size_t)s * 256 + t];
    }
    float r = acc / den + bias[t];
    if (DO_ELU) r = r > 0.f ? r : expf(r) - 1.f;
    outbuf[(size_t)n * 256 + t] = r;
}

__global__ void inv_norm_kernel(const float* __restrict__ emb1, const float* __restrict__ emb2,
                                float* __restrict__ invn) {
    int n = blockIdx.x, t = threadIdx.x;
    float v1 = emb1[(size_t)n * 256 + t];
    float v2 = emb2[(size_t)n * 256 + t];
    float s = v1 * v1 + v2 * v2;
    __shared__ float red[4];
    for (int o = 32; o > 0; o >>= 1) s += __shfl_xor(s, o, 64);
    if ((t & 63) == 0) red[t >> 6] = s;
    __syncthreads();
    if (t == 0) {
        float tot = red[0] + red[1] + red[2] + red[3];
        invn[n] = 1.f / fmaxf(sqrtf(tot), 1e-8f);
    }
}

__global__ __launch_bounds__(256) void loss_kernel(
        const float* __restrict__ emb1, const float* __restrict__ emb2,
        const float* __restrict__ invn,
        const int* __restrict__ walks, const int* __restrict__ negs,
        float* __restrict__ out) {
    __shared__ float anchor[512];
    __shared__ int pos_id[2 * WINDOW];
    __shared__ int pos_valid[2 * WINDOW];
    __shared__ float s_pos, s_neg;
    const int bl = blockIdx.x;
    const int b = bl / WALK_LEN, l = bl % WALK_LEN;
    const int t = threadIdx.x;
    if (t == 0) { s_pos = 0.f; s_neg = 0.f; }
    const int an = walks[b * WALK_LEN + l];
    const float inv_a = invn[an];
    for (int d = t; d < 512; d += 256) {
        float v = (d < 256) ? emb1[(size_t)an * 256 + d] : emb2[(size_t)an * 256 + (d - 256)];
        anchor[d] = v * inv_a;
    }
    if (t < 2 * WINDOW) {
        int off = (t < WINDOW) ? (t - WINDOW) : (t - WINDOW + 1);
        int pp = l + off;
        int valid = (pp >= 0 && pp < WALK_LEN) ? 1 : 0;
        int ppc = min(max(pp, 0), WALK_LEN - 1);
        pos_id[t] = walks[b * WALK_LEN + ppc];
        pos_valid[t] = valid;
    }
    __syncthreads();
    const int wave = t >> 6, lane = t & 63;
    for (int cand = wave; cand < 2 * WINDOW + NEG_S; cand += 4) {
        int node;
        if (cand < 2 * WINDOW) {
            if (!pos_valid[cand]) continue;
            node = pos_id[cand];
        } else {
            int s = cand - 2 * WINDOW;
            node = negs[(size_t)(b * WALK_LEN + l) * NEG_S + s];
            bool masked = false;
#pragma unroll
            for (int p = 0; p < 2 * WINDOW; p++)
                masked = masked || (pos_valid[p] && pos_id[p] == node);
            if (masked) continue;
        }
        const float ninv = invn[node];
        float part = 0.f;
        for (int d = lane; d < 512; d += 64) {
            float v = (d < 256) ? emb1[(size_t)node * 256 + d] : emb2[(size_t)node * 256 + (d - 256)];
            part += anchor[d] * v;
        }
        part *= ninv;
        for (int o = 32; o > 0; o >>= 1) part += __shfl_xor(part, o, 64);
        if (lane == 0) {
            float eres = expf(part / TEMP);
            if (cand < 2 * WINDOW) atomicAdd(&s_pos, eres);
            else                   atomicAdd(&s_neg, eres);
        }
    }
    __syncthreads();
    if (t == 0) {
        float term = (s_pos > 0.f) ? logf(1.f + s_neg / s_pos) : 0.f;
        atomicAdd(out, term);
    }
}

extern "C" void kernel_launch(void* const* d_in, const int* in_sizes, int n_in,
                              void* d_out, int out_size, void* d_ws, size_t ws_size,
                              hipStream_t stream) {
    const float* x      = (const float*)d_in[0];
    const int*   ei     = (const int*)d_in[1];
    const int*   walks  = (const int*)d_in[2];
    const int*   negs   = (const int*)d_in[3];
    const float* W1     = (const float*)d_in[4];
    const float* a_src1 = (const float*)d_in[5];
    const float* a_dst1 = (const float*)d_in[6];
    const float* b1     = (const float*)d_in[7];
    const float* W2     = (const float*)d_in[8];
    const float* a_src2 = (const float*)d_in[9];
    const float* a_dst2 = (const float*)d_in[10];
    const float* b2     = (const float*)d_in[11];
    float* out = (float*)d_out;

    float* ws = (float*)d_ws;
    size_t off = 0;
    float* xw    = ws + off; off += (size_t)N_NODES * 256;   // layer1 xw, reused as layer2 xw
    float* emb1  = ws + off; off += (size_t)N_NODES * 256;
    float* emb2  = ws + off; off += (size_t)N_NODES * 256;
    float* als1  = ws + off; off += N_NODES * HEADS_1;
    float* ald1  = ws + off; off += N_NODES * HEADS_1;
    float* als2  = ws + off; off += N_NODES;
    float* ald2  = ws + off; off += N_NODES;
    float* invn  = ws + off; off += N_NODES;
    int* deg       = (int*)(ws + off); off += N_NODES;
    int* excl      = (int*)(ws + off); off += N_NODES;
    int* bsum      = (int*)(ws + off); off += 256;
    int* row_start = (int*)(ws + off); off += N_NODES + 1;
    int* cursor    = (int*)(ws + off); off += N_NODES;
    int* srclist   = (int*)(ws + off); off += E_EDGES;

    hipMemsetAsync(out, 0, sizeof(float) * out_size, stream);
    hipMemsetAsync(deg, 0, sizeof(int) * N_NODES, stream);
    hipMemsetAsync(cursor, 0, sizeof(int) * N_NODES, stream);

    // ---- CSR build (shared by both layers) ----
    deg_kernel<<<(E_EDGES + 255) / 256, 256, 0, stream>>>(ei, deg);
    scan_a<<<SCAN_BLOCKS, 256, 0, stream>>>(deg, excl, bsum);
    scan_b<<<1, 256, 0, stream>>>(bsum);
    scan_c2<<<SCAN_BLOCKS, 256, 0, stream>>>(excl, bsum, row_start);
    bucket_kernel<<<(E_EDGES + 255) / 256, 256, 0, stream>>>(ei, row_start, cursor, srclist);

    // ---- layer 1 (heads=8, hid=32) ----
    gemm_rows<128><<<N_NODES / 16, 256, 0, stream>>>(x, W1, xw);
    al_kernel<<<(N_NODES * HEADS_1 + 255) / 256, 256, 0, stream>>>(xw, a_src1, a_dst1, als1, ald1, HEADS_1, HID_1);
    gat_gather<HEADS_1, true><<<N_NODES, 256, 0, stream>>>(row_start, srclist, als1, ald1, xw, b1, emb1);

    // ---- layer 2 (heads=1, hid=256) ----
    gemm_rows<256><<<N_NODES / 16, 256, 0, stream>>>(emb1, W2, xw);
    al_kernel<<<(N_NODES + 255) / 256, 256, 0, stream>>>(xw, a_src2, a_dst2, als2, ald2, 1, H1DIM);
    gat_gather<1, false><<<N_NODES, 256, 0, stream>>>(row_start, srclist, als2, ald2, xw, b2, emb2);

    // ---- contrastive loss ----
    inv_norm_kernel<<<N_NODES, 256, 0, stream>>>(emb1, emb2, invn);
    loss_kernel<<<NUM_WALKS * WALK_LEN, 256, 0, stream>>>(emb1, emb2, invn, walks, negs, out);
}

// Round 3
// 1228.503 us; speedup vs baseline: 2.3685x; 1.2459x over previous
//
#include <hip/hip_runtime.h>
#include <math.h>

#define N_NODES 50000
#define E_EDGES 800000
#define FDIM_IN 128
#define HID_1 32
#define HEADS_1 8
#define H1DIM 256
#define NUM_WALKS 512
#define WALK_LEN 64
#define WINDOW 5
#define NEG_S 10
#define TEMP 0.07f
#define INV_TEMP (1.0f / 0.07f)
#define NEG_SLOPE 0.2f

#define SCAN_BLOCKS ((N_NODES + 255) / 256)   // 196

typedef unsigned int uint;

__device__ __forceinline__ float leaky(float v) {
    return v > 0.f ? v : v * NEG_SLOPE;
}

__device__ __forceinline__ float bfl(uint u) { return __uint_as_float(u << 16); }
__device__ __forceinline__ float bfh(uint u) { return __uint_as_float(u & 0xffff0000u); }

__device__ __forceinline__ unsigned short f2bf(float x) {
    uint u = __float_as_uint(x);
    u = u + 0x7fffu + ((u >> 16) & 1u);   // round-to-nearest-even
    return (unsigned short)(u >> 16);
}

// ---------------- CSR build ----------------

__global__ void deg_kernel(const int* __restrict__ ei, int* __restrict__ deg) {
    int e = blockIdx.x * blockDim.x + threadIdx.x;
    if (e < E_EDGES) atomicAdd(&deg[ei[E_EDGES + e]], 1);
}

__global__ __launch_bounds__(256) void scan_a(const int* __restrict__ deg,
                                              int* __restrict__ excl,
                                              int* __restrict__ bsum) {
    __shared__ int s[256];
    int t = threadIdx.x;
    int i = blockIdx.x * 256 + t;
    int v = (i < N_NODES) ? deg[i] : 0;
    s[t] = v;
    __syncthreads();
    for (int off = 1; off < 256; off <<= 1) {
        int tmp = (t >= off) ? s[t - off] : 0;
        __syncthreads();
        s[t] += tmp;
        __syncthreads();
    }
    if (i < N_NODES) excl[i] = s[t] - v;
    if (t == 255) bsum[blockIdx.x] = s[255];
}

__global__ __launch_bounds__(256) void scan_b(int* __restrict__ bsum) {
    __shared__ int s[256];
    int t = threadIdx.x;
    int v = (t < SCAN_BLOCKS) ? bsum[t] : 0;
    s[t] = v;
    __syncthreads();
    for (int off = 1; off < 256; off <<= 1) {
        int tmp = (t >= off) ? s[t - off] : 0;
        __syncthreads();
        s[t] += tmp;
        __syncthreads();
    }
    if (t < SCAN_BLOCKS) bsum[t] = s[t] - v;   // exclusive
}

__global__ void scan_c2(int* __restrict__ excl, const int* __restrict__ bsum,
                        int* __restrict__ row_start) {
    int i = blockIdx.x * blockDim.x + threadIdx.x;
    if (i < N_NODES) row_start[i] = excl[i] + bsum[i >> 8];
    if (i == 0) row_start[N_NODES] = E_EDGES;
}

__global__ void bucket_kernel(const int* __restrict__ ei,
                              const int* __restrict__ row_start,
                              int* __restrict__ cursor,
                              int* __restrict__ srclist) {
    int e = blockIdx.x * blockDim.x + threadIdx.x;
    if (e >= E_EDGES) return;
    int dst = ei[E_EDGES + e];
    int pos = atomicAdd(&cursor[dst], 1);
    srclist[row_start[dst] + pos] = ei[e];
}

// ---------------- dense compute ----------------

template<int K>
__global__ __launch_bounds__(256) void gemm_rows(const float* __restrict__ X,
                                                 const float* __restrict__ W,
                                                 float* __restrict__ Y) {
    __shared__ float xs[16][K];
    const int row0 = blockIdx.x * 16;
    const int t = threadIdx.x;
    for (int i = t; i < 16 * K; i += 256) {
        int r = i / K, k = i % K;
        xs[r][k] = X[(size_t)(row0 + r) * K + k];
    }
    __syncthreads();
    float acc[16];
#pragma unroll
    for (int r = 0; r < 16; r++) acc[r] = 0.f;
    for (int k = 0; k < K; k++) {
        float w = W[k * 256 + t];
#pragma unroll
        for (int r = 0; r < 16; r++) acc[r] += xs[r][k] * w;
    }
#pragma unroll
    for (int r = 0; r < 16; r++) Y[(size_t)(row0 + r) * 256 + t] = acc[r];
}

__global__ void al_kernel(const float* __restrict__ xw,
                          const float* __restrict__ a_src, const float* __restrict__ a_dst,
                          float* __restrict__ als, float* __restrict__ ald,
                          int heads, int hid) {
    int i = blockIdx.x * blockDim.x + threadIdx.x;
    if (i >= N_NODES * heads) return;
    int n = i / heads, h = i % heads;
    const float* row = xw + (size_t)n * 256 + h * hid;
    const float* as = a_src + h * hid;
    const float* ad = a_dst + h * hid;
    float s = 0.f, d = 0.f;
    for (int c = 0; c < hid; c++) {
        float v = row[c];
        s += v * as[c];
        d += v * ad[c];
    }
    als[i] = s;
    ald[i] = d;
}

// one block per dst node: max -> exp/den/acc -> normalize+bias(+elu), no atomics
template<int H, bool DO_ELU>
__global__ __launch_bounds__(256) void gat_gather(
        const int* __restrict__ row_start, const int* __restrict__ srclist,
        const float* __restrict__ als, const float* __restrict__ ald,
        const float* __restrict__ xw, const float* __restrict__ bias,
        float* __restrict__ outbuf) {
    const int n = blockIdx.x;
    const int t = threadIdx.x;
    const int h = t / (256 / H);
    const float ald_n = ald[n * H + h];
    const float self_v = leaky(als[n * H + h] + ald_n);
    const int beg = row_start[n], end = row_start[n + 1];

    float mx = self_v;
    for (int i = beg; i < end; i++) {
        int s = srclist[i];
        mx = fmaxf(mx, leaky(als[s * H + h] + ald_n));
    }

    float den, acc;
    {
        float ex = expf(self_v - mx);
        den = ex;
        acc = ex * xw[(size_t)n * 256 + t];
    }
    for (int i = beg; i < end; i++) {
        int s = srclist[i];
        float ex = expf(leaky(als[s * H + h] + ald_n) - mx);
        den += ex;
        acc += ex * xw[(size_t)s * 256 + t];
    }
    float r = acc / den + bias[t];
    if (DO_ELU) r = r > 0.f ? r : expf(r) - 1.f;
    outbuf[(size_t)n * 256 + t] = r;
}

// normalize row of concat(emb1,emb2), pack to bf16: embn[n][0:512]
__global__ __launch_bounds__(256) void embn_kernel(const float* __restrict__ emb1,
                                                   const float* __restrict__ emb2,
                                                   uint* __restrict__ embn) {
    __shared__ float row[512];
    __shared__ float red[4];
    __shared__ float s_inv;
    const int n = blockIdx.x, t = threadIdx.x;
    float v1 = emb1[(size_t)n * 256 + t];
    float v2 = emb2[(size_t)n * 256 + t];
    row[t] = v1;
    row[256 + t] = v2;
    float s = v1 * v1 + v2 * v2;
    for (int o = 32; o > 0; o >>= 1) s += __shfl_xor(s, o, 64);
    if ((t & 63) == 0) red[t >> 6] = s;
    __syncthreads();
    if (t == 0) {
        float tot = red[0] + red[1] + red[2] + red[3];
        s_inv = 1.f / fmaxf(sqrtf(tot), 1e-8f);
    }
    __syncthreads();
    float inv = s_inv;
    float e0 = row[2 * t] * inv;
    float e1 = row[2 * t + 1] * inv;
    embn[(size_t)n * 256 + t] = (uint)f2bf(e0) | ((uint)f2bf(e1) << 16);
}

__device__ __forceinline__ float dot8(const float a[8], uint4 c) {
    float d;
    d  = a[0] * bfl(c.x) + a[1] * bfh(c.x);
    d += a[2] * bfl(c.y) + a[3] * bfh(c.y);
    d += a[4] * bfl(c.z) + a[5] * bfh(c.z);
    d += a[6] * bfl(c.w) + a[7] * bfh(c.w);
    return d;
}

// one block per walk; 64 walk-node rows cached in LDS (bf16); negs streamed
__global__ __launch_bounds__(256) void loss_walk_kernel(
        const uint* __restrict__ embn,     // 2-packed bf16, row stride 256 uints
        const int* __restrict__ walks, const int* __restrict__ negs,
        float* __restrict__ out) {
    __shared__ __align__(16) uint srows[64 * 256];   // 64 KB
    __shared__ int wids[64];
    __shared__ float wsum[4];
    const int b = blockIdx.x;
    const int t = threadIdx.x;
    const int w = t >> 6, lane = t & 63;
    if (t < 64) wids[t] = walks[b * WALK_LEN + t];
    __syncthreads();
    const uint4* g4 = (const uint4*)embn;            // row stride 64 uint4
    uint4* s4 = (uint4*)srows;
#pragma unroll 4
    for (int it = 0; it < 16; it++) {
        int r = it * 4 + w;
        s4[r * 64 + lane] = g4[(size_t)wids[r] * 64 + lane];
    }
    __syncthreads();

    float acc_term = 0.f;
    for (int l = w; l < WALK_LEN; l += 4) {
        // anchor fragment -> registers
        uint4 af = s4[l * 64 + lane];
        float a[8];
        a[0] = bfl(af.x); a[1] = bfh(af.x);
        a[2] = bfl(af.y); a[3] = bfh(af.y);
        a[4] = bfl(af.z); a[5] = bfh(af.z);
        a[6] = bfl(af.w); a[7] = bfh(af.w);

        int pid[2 * WINDOW];
        bool pval[2 * WINDOW];
#pragma unroll
        for (int j = 0; j < 2 * WINDOW; j++) {
            int off = (j < WINDOW) ? (j - WINDOW) : (j - WINDOW + 1);
            int p = l + off;
            pval[j] = (p >= 0 && p < WALK_LEN);
            int pc = p < 0 ? 0 : (p > WALK_LEN - 1 ? WALK_LEN - 1 : p);
            pid[j] = wids[pc];
        }

        float pos_sum = 0.f;
#pragma unroll
        for (int j = 0; j < 2 * WINDOW; j++) {
            if (!pval[j]) continue;                  // wave-uniform branch
            int off = (j < WINDOW) ? (j - WINDOW) : (j - WINDOW + 1);
            int p = l + off;
            float d = dot8(a, s4[p * 64 + lane]);
            for (int o = 32; o > 0; o >>= 1) d += __shfl_xor(d, o, 64);
            pos_sum += expf(d * INV_TEMP);
        }

        // prefetch all 10 neg rows + masks
        const int nbase = (b * WALK_LEN + l) * NEG_S;
        uint4 nf[NEG_S];
        bool nmask[NEG_S];
#pragma unroll
        for (int s = 0; s < NEG_S; s++) {
            int node = negs[nbase + s];
            bool msk = false;
#pragma unroll
            for (int j = 0; j < 2 * WINDOW; j++)
                msk = msk || (pval[j] && pid[j] == node);
            nmask[s] = msk;
            nf[s] = g4[(size_t)node * 64 + lane];
        }
        float neg_sum = 0.f;
#pragma unroll
        for (int s = 0; s < NEG_S; s++) {
            if (nmask[s]) continue;                  // wave-uniform branch
            float d = dot8(a, nf[s]);
            for (int o = 32; o > 0; o >>= 1) d += __shfl_xor(d, o, 64);
            neg_sum += expf(d * INV_TEMP);
        }
        acc_term += logf(1.f + neg_sum / pos_sum);   // pos_sum>0 always (window covers every l)
    }
    if (lane == 0) wsum[w] = acc_term;
    __syncthreads();
    if (t == 0) atomicAdd(out, wsum[0] + wsum[1] + wsum[2] + wsum[3]);
}

extern "C" void kernel_launch(void* const* d_in, const int* in_sizes, int n_in,
                              void* d_out, int out_size, void* d_ws, size_t ws_size,
                              hipStream_t stream) {
    const float* x      = (const float*)d_in[0];
    const int*   ei     = (const int*)d_in[1];
    const int*   walks  = (const int*)d_in[2];
    const int*   negs   = (const int*)d_in[3];
    const float* W1     = (const float*)d_in[4];
    const float* a_src1 = (const float*)d_in[5];
    const float* a_dst1 = (const float*)d_in[6];
    const float* b1     = (const float*)d_in[7];
    const float* W2     = (const float*)d_in[8];
    const float* a_src2 = (const float*)d_in[9];
    const float* a_dst2 = (const float*)d_in[10];
    const float* b2     = (const float*)d_in[11];
    float* out = (float*)d_out;

    float* ws = (float*)d_ws;
    size_t off = 0;
    float* xw    = ws + off; off += (size_t)N_NODES * 256;   // layer xw; later aliased as embn (bf16 50000x512 = same bytes)
    float* emb1  = ws + off; off += (size_t)N_NODES * 256;
    float* emb2  = ws + off; off += (size_t)N_NODES * 256;
    float* als1  = ws + off; off += N_NODES * HEADS_1;
    float* ald1  = ws + off; off += N_NODES * HEADS_1;
    float* als2  = ws + off; off += N_NODES;
    float* ald2  = ws + off; off += N_NODES;
    int* deg       = (int*)(ws + off); off += N_NODES;
    int* excl      = (int*)(ws + off); off += N_NODES;
    int* bsum      = (int*)(ws + off); off += 256;
    int* row_start = (int*)(ws + off); off += N_NODES + 1;
    int* cursor    = (int*)(ws + off); off += N_NODES;
    int* srclist   = (int*)(ws + off); off += E_EDGES;
    uint* embn = (uint*)xw;   // xw is dead after gat_gather layer2

    hipMemsetAsync(out, 0, sizeof(float) * out_size, stream);
    hipMemsetAsync(deg, 0, sizeof(int) * N_NODES, stream);
    hipMemsetAsync(cursor, 0, sizeof(int) * N_NODES, stream);

    // ---- CSR build (shared by both layers) ----
    deg_kernel<<<(E_EDGES + 255) / 256, 256, 0, stream>>>(ei, deg);
    scan_a<<<SCAN_BLOCKS, 256, 0, stream>>>(deg, excl, bsum);
    scan_b<<<1, 256, 0, stream>>>(bsum);
    scan_c2<<<SCAN_BLOCKS, 256, 0, stream>>>(excl, bsum, row_start);
    bucket_kernel<<<(E_EDGES + 255) / 256, 256, 0, stream>>>(ei, row_start, cursor, srclist);

    // ---- layer 1 (heads=8, hid=32) ----
    gemm_rows<128><<<N_NODES / 16, 256, 0, stream>>>(x, W1, xw);
    al_kernel<<<(N_NODES * HEADS_1 + 255) / 256, 256, 0, stream>>>(xw, a_src1, a_dst1, als1, ald1, HEADS_1, HID_1);
    gat_gather<HEADS_1, true><<<N_NODES, 256, 0, stream>>>(row_start, srclist, als1, ald1, xw, b1, emb1);

    // ---- layer 2 (heads=1, hid=256) ----
    gemm_rows<256><<<N_NODES / 16, 256, 0, stream>>>(emb1, W2, xw);
    al_kernel<<<(N_NODES + 255) / 256, 256, 0, stream>>>(xw, a_src2, a_dst2, als2, ald2, 1, H1DIM);
    gat_gather<1, false><<<N_NODES, 256, 0, stream>>>(row_start, srclist, als2, ald2, xw, b2, emb2);

    // ---- contrastive loss ----
    embn_kernel<<<N_NODES, 256, 0, stream>>>(emb1, emb2, embn);
    loss_walk_kernel<<<NUM_WALKS, 256, 0, stream>>>(embn, walks, negs, out);
}

// Round 4
// 949.200 us; speedup vs baseline: 3.0654x; 1.2943x over previous
//
#include <hip/hip_runtime.h>
#include <math.h>

#define N_NODES 50000
#define E_EDGES 800000
#define FDIM_IN 128
#define HID_1 32
#define HEADS_1 8
#define H1DIM 256
#define NUM_WALKS 512
#define WALK_LEN 64
#define WINDOW 5
#define NEG_S 10
#define TEMP 0.07f
#define INV_TEMP (1.0f / 0.07f)
#define NEG_SLOPE 0.2f

#define SCAN_BLOCKS ((N_NODES + 255) / 256)   // 196

typedef unsigned int uint;

__device__ __forceinline__ float leaky(float v) {
    return v > 0.f ? v : v * NEG_SLOPE;
}

__device__ __forceinline__ float bfl(uint u) { return __uint_as_float(u << 16); }
__device__ __forceinline__ float bfh(uint u) { return __uint_as_float(u & 0xffff0000u); }

__device__ __forceinline__ unsigned short f2bf(float x) {
    uint u = __float_as_uint(x);
    u = u + 0x7fffu + ((u >> 16) & 1u);   // round-to-nearest-even
    return (unsigned short)(u >> 16);
}

// ---------------- CSR build ----------------

__global__ void deg_kernel(const int* __restrict__ ei, int* __restrict__ deg) {
    int e = blockIdx.x * blockDim.x + threadIdx.x;
    if (e < E_EDGES) atomicAdd(&deg[ei[E_EDGES + e]], 1);
}

__global__ __launch_bounds__(256) void scan_a(const int* __restrict__ deg,
                                              int* __restrict__ excl,
                                              int* __restrict__ bsum) {
    __shared__ int s[256];
    int t = threadIdx.x;
    int i = blockIdx.x * 256 + t;
    int v = (i < N_NODES) ? deg[i] : 0;
    s[t] = v;
    __syncthreads();
    for (int off = 1; off < 256; off <<= 1) {
        int tmp = (t >= off) ? s[t - off] : 0;
        __syncthreads();
        s[t] += tmp;
        __syncthreads();
    }
    if (i < N_NODES) excl[i] = s[t] - v;
    if (t == 255) bsum[blockIdx.x] = s[255];
}

__global__ __launch_bounds__(256) void scan_b(int* __restrict__ bsum) {
    __shared__ int s[256];
    int t = threadIdx.x;
    int v = (t < SCAN_BLOCKS) ? bsum[t] : 0;
    s[t] = v;
    __syncthreads();
    for (int off = 1; off < 256; off <<= 1) {
        int tmp = (t >= off) ? s[t - off] : 0;
        __syncthreads();
        s[t] += tmp;
        __syncthreads();
    }
    if (t < SCAN_BLOCKS) bsum[t] = s[t] - v;   // exclusive
}

__global__ void scan_c2(int* __restrict__ excl, const int* __restrict__ bsum,
                        int* __restrict__ row_start) {
    int i = blockIdx.x * blockDim.x + threadIdx.x;
    if (i < N_NODES) row_start[i] = excl[i] + bsum[i >> 8];
    if (i == 0) row_start[N_NODES] = E_EDGES;
}

__global__ void bucket_kernel(const int* __restrict__ ei,
                              const int* __restrict__ row_start,
                              int* __restrict__ cursor,
                              int* __restrict__ srclist) {
    int e = blockIdx.x * blockDim.x + threadIdx.x;
    if (e >= E_EDGES) return;
    int dst = ei[E_EDGES + e];
    int pos = atomicAdd(&cursor[dst], 1);
    srclist[row_start[dst] + pos] = ei[e];
}

// ---------------- dense compute ----------------

// Y[n][j] = sum_k X[n][k]*W[k][j], output packed bf16 (ushort per element)
template<int K>
__global__ __launch_bounds__(256) void gemm_rows(const float* __restrict__ X,
                                                 const float* __restrict__ W,
                                                 unsigned short* __restrict__ Yb) {
    __shared__ float xs[16][K];
    const int row0 = blockIdx.x * 16;
    const int t = threadIdx.x;
    for (int i = t; i < 16 * K; i += 256) {
        int r = i / K, k = i % K;
        xs[r][k] = X[(size_t)(row0 + r) * K + k];
    }
    __syncthreads();
    float acc[16];
#pragma unroll
    for (int r = 0; r < 16; r++) acc[r] = 0.f;
    for (int k = 0; k < K; k++) {
        float w = W[k * 256 + t];
#pragma unroll
        for (int r = 0; r < 16; r++) acc[r] += xs[r][k] * w;
    }
#pragma unroll
    for (int r = 0; r < 16; r++) Yb[(size_t)(row0 + r) * 256 + t] = f2bf(acc[r]);
}

// one wave per node: als/ald from bf16 row, shuffle-reduced per head
template<int H>
__global__ __launch_bounds__(256) void al_wave_kernel(
        const uint* __restrict__ xwb,                    // row stride 128 uints
        const float* __restrict__ a_src, const float* __restrict__ a_dst,
        float* __restrict__ als, float* __restrict__ ald) {
    int wid = (blockIdx.x * 256 + threadIdx.x) >> 6;
    int lane = threadIdx.x & 63;
    if (wid >= N_NODES) return;
    uint2 u = ((const uint2*)(xwb + (size_t)wid * 128))[lane];
    int col = lane * 4;
    float x0 = bfl(u.x), x1 = bfh(u.x), x2 = bfl(u.y), x3 = bfh(u.y);
    // a_src/a_dst are [H][hid] flattened = indexable by col directly
    float s = x0 * a_src[col] + x1 * a_src[col + 1] + x2 * a_src[col + 2] + x3 * a_src[col + 3];
    float d = x0 * a_dst[col] + x1 * a_dst[col + 1] + x2 * a_dst[col + 2] + x3 * a_dst[col + 3];
#pragma unroll
    for (int o = 32 / H; o > 0; o >>= 1) {
        s += __shfl_xor(s, o, 64);
        d += __shfl_xor(d, o, 64);
    }
    if ((lane & (64 / H - 1)) == 0) {
        int h = lane / (64 / H);
        als[wid * H + h] = s;
        ald[wid * H + h] = d;
    }
}

// one block per dst node, single pass, no max (logits bounded), bf16 rows
template<int H, bool DO_ELU>
__global__ __launch_bounds__(256) void gat_gather(
        const int* __restrict__ row_start, const int* __restrict__ srclist,
        const float* __restrict__ als, const float* __restrict__ ald,
        const uint* __restrict__ xwb,                    // row stride 128 uints
        const float* __restrict__ bias,
        float* __restrict__ outbuf) {
    const int n = blockIdx.x;
    const int t = threadIdx.x;
    const int h = t / (256 / H);
    const int col = t >> 1, sel = t & 1;
    const float ald_n = ald[n * H + h];
    const int beg = row_start[n], end = row_start[n + 1];

    float den, acc;
    {
        float ex = __expf(leaky(als[n * H + h] + ald_n));
        uint xv = xwb[(size_t)n * 128 + col];
        den = ex;
        acc = ex * __uint_as_float(sel ? (xv & 0xffff0000u) : (xv << 16));
    }
    int s_next = (beg < end) ? srclist[beg] : 0;
    for (int i = beg; i < end; i++) {
        int s = s_next;
        s_next = srclist[min(i + 1, end - 1)];
        float al = als[s * H + h];
        uint xv = xwb[(size_t)s * 128 + col];
        float ex = __expf(leaky(al + ald_n));
        den += ex;
        acc += ex * __uint_as_float(sel ? (xv & 0xffff0000u) : (xv << 16));
    }
    float r = acc / den + bias[t];
    if (DO_ELU) r = r > 0.f ? r : __expf(r) - 1.f;
    outbuf[(size_t)n * 256 + t] = r;
}

// normalize row of concat(emb1,emb2), pack to bf16: embn[n][0:512]
__global__ __launch_bounds__(256) void embn_kernel(const float* __restrict__ emb1,
                                                   const float* __restrict__ emb2,
                                                   uint* __restrict__ embn) {
    __shared__ float row[512];
    __shared__ float red[4];
    __shared__ float s_inv;
    const int n = blockIdx.x, t = threadIdx.x;
    float v1 = emb1[(size_t)n * 256 + t];
    float v2 = emb2[(size_t)n * 256 + t];
    row[t] = v1;
    row[256 + t] = v2;
    float s = v1 * v1 + v2 * v2;
    for (int o = 32; o > 0; o >>= 1) s += __shfl_xor(s, o, 64);
    if ((t & 63) == 0) red[t >> 6] = s;
    __syncthreads();
    if (t == 0) {
        float tot = red[0] + red[1] + red[2] + red[3];
        s_inv = 1.f / fmaxf(sqrtf(tot), 1e-8f);
    }
    __syncthreads();
    float inv = s_inv;
    float e0 = row[2 * t] * inv;
    float e1 = row[2 * t + 1] * inv;
    embn[(size_t)n * 256 + t] = (uint)f2bf(e0) | ((uint)f2bf(e1) << 16);
}

__device__ __forceinline__ float dot8(const float a[8], uint4 c) {
    float d;
    d  = a[0] * bfl(c.x) + a[1] * bfh(c.x);
    d += a[2] * bfl(c.y) + a[3] * bfh(c.y);
    d += a[4] * bfl(c.z) + a[5] * bfh(c.z);
    d += a[6] * bfl(c.w) + a[7] * bfh(c.w);
    return d;
}

// one block per walk; 64 walk-node rows cached in LDS (bf16); negs streamed
__global__ __launch_bounds__(256) void loss_walk_kernel(
        const uint* __restrict__ embn,     // 2-packed bf16, row stride 256 uints
        const int* __restrict__ walks, const int* __restrict__ negs,
        float* __restrict__ out) {
    __shared__ __align__(16) uint srows[64 * 256];   // 64 KB
    __shared__ int wids[64];
    __shared__ float wsum[4];
    const int b = blockIdx.x;
    const int t = threadIdx.x;
    const int w = t >> 6, lane = t & 63;
    if (t < 64) wids[t] = walks[b * WALK_LEN + t];
    __syncthreads();
    const uint4* g4 = (const uint4*)embn;            // row stride 64 uint4
    uint4* s4 = (uint4*)srows;
#pragma unroll 4
    for (int it = 0; it < 16; it++) {
        int r = it * 4 + w;
        s4[r * 64 + lane] = g4[(size_t)wids[r] * 64 + lane];
    }
    __syncthreads();

    float acc_term = 0.f;
    for (int l = w; l < WALK_LEN; l += 4) {
        uint4 af = s4[l * 64 + lane];
        float a[8];
        a[0] = bfl(af.x); a[1] = bfh(af.x);
        a[2] = bfl(af.y); a[3] = bfh(af.y);
        a[4] = bfl(af.z); a[5] = bfh(af.z);
        a[6] = bfl(af.w); a[7] = bfh(af.w);

        int pid[2 * WINDOW];
        bool pval[2 * WINDOW];
#pragma unroll
        for (int j = 0; j < 2 * WINDOW; j++) {
            int off = (j < WINDOW) ? (j - WINDOW) : (j - WINDOW + 1);
            int p = l + off;
            pval[j] = (p >= 0 && p < WALK_LEN);
            int pc = p < 0 ? 0 : (p > WALK_LEN - 1 ? WALK_LEN - 1 : p);
            pid[j] = wids[pc];
        }

        float pos_sum = 0.f;
#pragma unroll
        for (int j = 0; j < 2 * WINDOW; j++) {
            if (!pval[j]) continue;                  // wave-uniform branch
            int off = (j < WINDOW) ? (j - WINDOW) : (j - WINDOW + 1);
            int p = l + off;
            float d = dot8(a, s4[p * 64 + lane]);
            for (int o = 32; o > 0; o >>= 1) d += __shfl_xor(d, o, 64);
            pos_sum += expf(d * INV_TEMP);
        }

        const int nbase = (b * WALK_LEN + l) * NEG_S;
        uint4 nf[NEG_S];
        bool nmask[NEG_S];
#pragma unroll
        for (int s = 0; s < NEG_S; s++) {
            int node = negs[nbase + s];
            bool msk = false;
#pragma unroll
            for (int j = 0; j < 2 * WINDOW; j++)
                msk = msk || (pval[j] && pid[j] == node);
            nmask[s] = msk;
            nf[s] = g4[(size_t)node * 64 + lane];
        }
        float neg_sum = 0.f;
#pragma unroll
        for (int s = 0; s < NEG_S; s++) {
            if (nmask[s]) continue;                  // wave-uniform branch
            float d = dot8(a, nf[s]);
            for (int o = 32; o > 0; o >>= 1) d += __shfl_xor(d, o, 64);
            neg_sum += expf(d * INV_TEMP);
        }
        acc_term += logf(1.f + neg_sum / pos_sum);   // pos_sum>0 always
    }
    if (lane == 0) wsum[w] = acc_term;
    __syncthreads();
    if (t == 0) atomicAdd(out, wsum[0] + wsum[1] + wsum[2] + wsum[3]);
}

extern "C" void kernel_launch(void* const* d_in, const int* in_sizes, int n_in,
                              void* d_out, int out_size, void* d_ws, size_t ws_size,
                              hipStream_t stream) {
    const float* x      = (const float*)d_in[0];
    const int*   ei     = (const int*)d_in[1];
    const int*   walks  = (const int*)d_in[2];
    const int*   negs   = (const int*)d_in[3];
    const float* W1     = (const float*)d_in[4];
    const float* a_src1 = (const float*)d_in[5];
    const float* a_dst1 = (const float*)d_in[6];
    const float* b1     = (const float*)d_in[7];
    const float* W2     = (const float*)d_in[8];
    const float* a_src2 = (const float*)d_in[9];
    const float* a_dst2 = (const float*)d_in[10];
    const float* b2     = (const float*)d_in[11];
    float* out = (float*)d_out;

    float* ws = (float*)d_ws;
    size_t off = 0;
    // region0: xwb (bf16 xw, 25.6 MB) during GAT layers; embn (51.2 MB) after
    float* region0 = ws + off; off += (size_t)N_NODES * 256;
    float* emb1  = ws + off; off += (size_t)N_NODES * 256;
    float* emb2  = ws + off; off += (size_t)N_NODES * 256;
    float* als1  = ws + off; off += N_NODES * HEADS_1;
    float* ald1  = ws + off; off += N_NODES * HEADS_1;
    float* als2  = ws + off; off += N_NODES;
    float* ald2  = ws + off; off += N_NODES;
    int* deg       = (int*)(ws + off); off += N_NODES;
    int* excl      = (int*)(ws + off); off += N_NODES;
    int* bsum      = (int*)(ws + off); off += 256;
    int* row_start = (int*)(ws + off); off += N_NODES + 1;
    int* cursor    = (int*)(ws + off); off += N_NODES;
    int* srclist   = (int*)(ws + off); off += E_EDGES;
    unsigned short* xwb = (unsigned short*)region0;  // [N][256] bf16
    uint* embn = (uint*)region0;                     // [N][256] 2-packed bf16 (xwb dead)

    hipMemsetAsync(out, 0, sizeof(float) * out_size, stream);
    hipMemsetAsync(deg, 0, sizeof(int) * N_NODES, stream);
    hipMemsetAsync(cursor, 0, sizeof(int) * N_NODES, stream);

    // ---- CSR build (shared by both layers) ----
    deg_kernel<<<(E_EDGES + 255) / 256, 256, 0, stream>>>(ei, deg);
    scan_a<<<SCAN_BLOCKS, 256, 0, stream>>>(deg, excl, bsum);
    scan_b<<<1, 256, 0, stream>>>(bsum);
    scan_c2<<<SCAN_BLOCKS, 256, 0, stream>>>(excl, bsum, row_start);
    bucket_kernel<<<(E_EDGES + 255) / 256, 256, 0, stream>>>(ei, row_start, cursor, srclist);

    // ---- layer 1 (heads=8, hid=32) ----
    gemm_rows<128><<<N_NODES / 16, 256, 0, stream>>>(x, W1, xwb);
    al_wave_kernel<HEADS_1><<<(N_NODES * 64 + 255) / 256, 256, 0, stream>>>(
        (const uint*)xwb, a_src1, a_dst1, als1, ald1);
    gat_gather<HEADS_1, true><<<N_NODES, 256, 0, stream>>>(
        row_start, srclist, als1, ald1, (const uint*)xwb, b1, emb1);

    // ---- layer 2 (heads=1, hid=256) ----
    gemm_rows<256><<<N_NODES / 16, 256, 0, stream>>>(emb1, W2, xwb);
    al_wave_kernel<1><<<(N_NODES * 64 + 255) / 256, 256, 0, stream>>>(
        (const uint*)xwb, a_src2, a_dst2, als2, ald2);
    gat_gather<1, false><<<N_NODES, 256, 0, stream>>>(
        row_start, srclist, als2, ald2, (const uint*)xwb, b2, emb2);

    // ---- contrastive loss ----
    embn_kernel<<<N_NODES, 256, 0, stream>>>(emb1, emb2, embn);
    loss_walk_kernel<<<NUM_WALKS, 256, 0, stream>>>(embn, walks, negs, out);
}

// Round 5
// 696.509 us; speedup vs baseline: 4.1775x; 1.3628x over previous
//
#include <hip/hip_runtime.h>
#include <math.h>

#define N_NODES 50000
#define E_EDGES 800000
#define FDIM_IN 128
#define HID_1 32
#define HEADS_1 8
#define H1DIM 256
#define NUM_WALKS 512
#define WALK_LEN 64
#define WINDOW 5
#define NEG_S 10
#define TEMP 0.07f
#define INV_TEMP (1.0f / 0.07f)
#define NEG_SLOPE 0.2f

#define SCAN_BLOCKS ((N_NODES + 255) / 256)   // 196

typedef unsigned int uint;

__device__ __forceinline__ float leaky(float v) {
    return v > 0.f ? v : v * NEG_SLOPE;
}

__device__ __forceinline__ float bfl(uint u) { return __uint_as_float(u << 16); }
__device__ __forceinline__ float bfh(uint u) { return __uint_as_float(u & 0xffff0000u); }

__device__ __forceinline__ unsigned short f2bf(float x) {
    uint u = __float_as_uint(x);
    u = u + 0x7fffu + ((u >> 16) & 1u);   // round-to-nearest-even
    return (unsigned short)(u >> 16);
}

// ---------------- CSR build ----------------

__global__ void deg_kernel(const int* __restrict__ ei, int* __restrict__ deg) {
    int e = blockIdx.x * blockDim.x + threadIdx.x;
    if (e < E_EDGES) atomicAdd(&deg[ei[E_EDGES + e]], 1);
}

__global__ __launch_bounds__(256) void scan_a(const int* __restrict__ deg,
                                              int* __restrict__ excl,
                                              int* __restrict__ bsum) {
    __shared__ int s[256];
    int t = threadIdx.x;
    int i = blockIdx.x * 256 + t;
    int v = (i < N_NODES) ? deg[i] : 0;
    s[t] = v;
    __syncthreads();
    for (int off = 1; off < 256; off <<= 1) {
        int tmp = (t >= off) ? s[t - off] : 0;
        __syncthreads();
        s[t] += tmp;
        __syncthreads();
    }
    if (i < N_NODES) excl[i] = s[t] - v;
    if (t == 255) bsum[blockIdx.x] = s[255];
}

__global__ __launch_bounds__(256) void scan_b(int* __restrict__ bsum) {
    __shared__ int s[256];
    int t = threadIdx.x;
    int v = (t < SCAN_BLOCKS) ? bsum[t] : 0;
    s[t] = v;
    __syncthreads();
    for (int off = 1; off < 256; off <<= 1) {
        int tmp = (t >= off) ? s[t - off] : 0;
        __syncthreads();
        s[t] += tmp;
        __syncthreads();
    }
    if (t < SCAN_BLOCKS) bsum[t] = s[t] - v;   // exclusive
}

__global__ void scan_c2(int* __restrict__ excl, const int* __restrict__ bsum,
                        int* __restrict__ row_start) {
    int i = blockIdx.x * blockDim.x + threadIdx.x;
    if (i < N_NODES) row_start[i] = excl[i] + bsum[i >> 8];
    if (i == 0) row_start[N_NODES] = E_EDGES;
}

__global__ void bucket_kernel(const int* __restrict__ ei,
                              const int* __restrict__ row_start,
                              int* __restrict__ cursor,
                              int* __restrict__ srclist) {
    int e = blockIdx.x * blockDim.x + threadIdx.x;
    if (e >= E_EDGES) return;
    int dst = ei[E_EDGES + e];
    int pos = atomicAdd(&cursor[dst], 1);
    srclist[row_start[dst] + pos] = ei[e];
}

// ---------------- dense compute ----------------

// Y[n][j] = sum_k X[n][k]*W[k][j], output packed bf16 (ushort per element)
template<int K>
__global__ __launch_bounds__(256) void gemm_rows(const float* __restrict__ X,
                                                 const float* __restrict__ W,
                                                 unsigned short* __restrict__ Yb) {
    __shared__ float xs[16][K];
    const int row0 = blockIdx.x * 16;
    const int t = threadIdx.x;
    for (int i = t; i < 16 * K; i += 256) {
        int r = i / K, k = i % K;
        xs[r][k] = X[(size_t)(row0 + r) * K + k];
    }
    __syncthreads();
    float acc[16];
#pragma unroll
    for (int r = 0; r < 16; r++) acc[r] = 0.f;
    for (int k = 0; k < K; k++) {
        float w = W[k * 256 + t];
#pragma unroll
        for (int r = 0; r < 16; r++) acc[r] += xs[r][k] * w;
    }
#pragma unroll
    for (int r = 0; r < 16; r++) Yb[(size_t)(row0 + r) * 256 + t] = f2bf(acc[r]);
}

// one wave per node: als/ald from bf16 row, shuffle-reduced per head
template<int H>
__global__ __launch_bounds__(256) void al_wave_kernel(
        const uint* __restrict__ xwb,                    // row stride 128 uints
        const float* __restrict__ a_src, const float* __restrict__ a_dst,
        float* __restrict__ als, float* __restrict__ ald) {
    int wid = (blockIdx.x * 256 + threadIdx.x) >> 6;
    int lane = threadIdx.x & 63;
    if (wid >= N_NODES) return;
    uint2 u = ((const uint2*)(xwb + (size_t)wid * 128))[lane];
    int col = lane * 4;
    float x0 = bfl(u.x), x1 = bfh(u.x), x2 = bfl(u.y), x3 = bfh(u.y);
    float s = x0 * a_src[col] + x1 * a_src[col + 1] + x2 * a_src[col + 2] + x3 * a_src[col + 3];
    float d = x0 * a_dst[col] + x1 * a_dst[col + 1] + x2 * a_dst[col + 2] + x3 * a_dst[col + 3];
#pragma unroll
    for (int o = 32 / H; o > 0; o >>= 1) {
        s += __shfl_xor(s, o, 64);
        d += __shfl_xor(d, o, 64);
    }
    if ((lane & (64 / H - 1)) == 0) {
        int h = lane / (64 / H);
        als[wid * H + h] = s;
        ald[wid * H + h] = d;
    }
}

#define UN 8

// layer-1 gather: wave per node, 8-deep batched edge loads, ELU, fp32 out
__global__ __launch_bounds__(256) void gat_gather1(
        const int* __restrict__ row_start, const int* __restrict__ srclist,
        const float* __restrict__ als, const float* __restrict__ ald,
        const uint* __restrict__ xwb,                    // row stride 128 uints
        const float* __restrict__ bias,
        float* __restrict__ emb1) {
    const int wid = blockIdx.x * 4 + (threadIdx.x >> 6);
    const int lane = threadIdx.x & 63;
    const int h = lane >> 3;                             // head = (4*lane)/32
    const float ald_n = ald[wid * HEADS_1 + h];
    const int beg = row_start[wid], end = row_start[wid + 1];
    const uint2* rowp = (const uint2*)xwb;               // row stride 64 uint2

    float ex0 = __expf(leaky(als[wid * HEADS_1 + h] + ald_n));
    uint2 u = rowp[(size_t)wid * 64 + lane];
    float den = ex0;
    float a0 = ex0 * bfl(u.x), a1 = ex0 * bfh(u.x);
    float a2 = ex0 * bfl(u.y), a3 = ex0 * bfh(u.y);

    for (int i = beg; i < end; i += UN) {
        int ss[UN]; uint2 rr[UN]; float ee[UN];
#pragma unroll
        for (int j = 0; j < UN; j++) ss[j] = srclist[min(i + j, end - 1)];
#pragma unroll
        for (int j = 0; j < UN; j++) rr[j] = rowp[(size_t)ss[j] * 64 + lane];
#pragma unroll
        for (int j = 0; j < UN; j++) ee[j] = als[ss[j] * HEADS_1 + h];
#pragma unroll
        for (int j = 0; j < UN; j++) {
            float ex = (i + j < end) ? __expf(leaky(ee[j] + ald_n)) : 0.f;
            den += ex;
            a0 += ex * bfl(rr[j].x); a1 += ex * bfh(rr[j].x);
            a2 += ex * bfl(rr[j].y); a3 += ex * bfh(rr[j].y);
        }
    }
    float inv = 1.f / den;
    float4 bv = ((const float4*)bias)[lane];
    float4 r;
    r.x = a0 * inv + bv.x; r.y = a1 * inv + bv.y;
    r.z = a2 * inv + bv.z; r.w = a3 * inv + bv.w;
    r.x = r.x > 0.f ? r.x : __expf(r.x) - 1.f;
    r.y = r.y > 0.f ? r.y : __expf(r.y) - 1.f;
    r.z = r.z > 0.f ? r.z : __expf(r.z) - 1.f;
    r.w = r.w > 0.f ? r.w : __expf(r.w) - 1.f;
    ((float4*)emb1)[(size_t)wid * 64 + lane] = r;
}

// layer-2 gather fused with normalize+pack: emb2 never materialized
__global__ __launch_bounds__(256) void gat_gather2(
        const int* __restrict__ row_start, const int* __restrict__ srclist,
        const float* __restrict__ als, const float* __restrict__ ald,
        const uint* __restrict__ xwb,                    // row stride 128 uints
        const float* __restrict__ bias,
        const float* __restrict__ emb1,
        uint* __restrict__ embn) {                       // row stride 256 uints
    const int wid = blockIdx.x * 4 + (threadIdx.x >> 6);
    const int lane = threadIdx.x & 63;
    const float ald_n = ald[wid];
    const int beg = row_start[wid], end = row_start[wid + 1];
    const uint2* rowp = (const uint2*)xwb;

    float ex0 = __expf(leaky(als[wid] + ald_n));
    uint2 u = rowp[(size_t)wid * 64 + lane];
    float den = ex0;
    float a0 = ex0 * bfl(u.x), a1 = ex0 * bfh(u.x);
    float a2 = ex0 * bfl(u.y), a3 = ex0 * bfh(u.y);

    for (int i = beg; i < end; i += UN) {
        int ss[UN]; uint2 rr[UN]; float ee[UN];
#pragma unroll
        for (int j = 0; j < UN; j++) ss[j] = srclist[min(i + j, end - 1)];
#pragma unroll
        for (int j = 0; j < UN; j++) rr[j] = rowp[(size_t)ss[j] * 64 + lane];
#pragma unroll
        for (int j = 0; j < UN; j++) ee[j] = als[ss[j]];
#pragma unroll
        for (int j = 0; j < UN; j++) {
            float ex = (i + j < end) ? __expf(leaky(ee[j] + ald_n)) : 0.f;
            den += ex;
            a0 += ex * bfl(rr[j].x); a1 += ex * bfh(rr[j].x);
            a2 += ex * bfl(rr[j].y); a3 += ex * bfh(rr[j].y);
        }
    }
    float inv = 1.f / den;
    float4 bv = ((const float4*)bias)[lane];
    float4 e2;
    e2.x = a0 * inv + bv.x; e2.y = a1 * inv + bv.y;
    e2.z = a2 * inv + bv.z; e2.w = a3 * inv + bv.w;
    float4 e1 = ((const float4*)emb1)[(size_t)wid * 64 + lane];

    float ssum = e1.x * e1.x + e1.y * e1.y + e1.z * e1.z + e1.w * e1.w
               + e2.x * e2.x + e2.y * e2.y + e2.z * e2.z + e2.w * e2.w;
#pragma unroll
    for (int o = 32; o > 0; o >>= 1) ssum += __shfl_xor(ssum, o, 64);
    float innv = 1.f / fmaxf(sqrtf(ssum), 1e-8f);

    uint2 p1, p2;
    p1.x = (uint)f2bf(e1.x * innv) | ((uint)f2bf(e1.y * innv) << 16);
    p1.y = (uint)f2bf(e1.z * innv) | ((uint)f2bf(e1.w * innv) << 16);
    p2.x = (uint)f2bf(e2.x * innv) | ((uint)f2bf(e2.y * innv) << 16);
    p2.y = (uint)f2bf(e2.z * innv) | ((uint)f2bf(e2.w * innv) << 16);
    ((uint2*)embn)[(size_t)wid * 128 + lane] = p1;        // cols 0..255   (emb1 part)
    ((uint2*)embn)[(size_t)wid * 128 + 64 + lane] = p2;   // cols 256..511 (emb2 part)
}

__device__ __forceinline__ float dot8(const float a[8], uint4 c) {
    float d;
    d  = a[0] * bfl(c.x) + a[1] * bfh(c.x);
    d += a[2] * bfl(c.y) + a[3] * bfh(c.y);
    d += a[4] * bfl(c.z) + a[5] * bfh(c.z);
    d += a[6] * bfl(c.w) + a[7] * bfh(c.w);
    return d;
}

// one block per walk; 64 walk-node rows cached in LDS (bf16); negs streamed
__global__ __launch_bounds__(256) void loss_walk_kernel(
        const uint* __restrict__ embn,     // 2-packed bf16, row stride 256 uints
        const int* __restrict__ walks, const int* __restrict__ negs,
        float* __restrict__ out) {
    __shared__ __align__(16) uint srows[64 * 256];   // 64 KB
    __shared__ int wids[64];
    __shared__ float wsum[4];
    const int b = blockIdx.x;
    const int t = threadIdx.x;
    const int w = t >> 6, lane = t & 63;
    if (t < 64) wids[t] = walks[b * WALK_LEN + t];
    __syncthreads();
    const uint4* g4 = (const uint4*)embn;            // row stride 64 uint4
    uint4* s4 = (uint4*)srows;
#pragma unroll 4
    for (int it = 0; it < 16; it++) {
        int r = it * 4 + w;
        s4[r * 64 + lane] = g4[(size_t)wids[r] * 64 + lane];
    }
    __syncthreads();

    float acc_term = 0.f;
    for (int l = w; l < WALK_LEN; l += 4) {
        uint4 af = s4[l * 64 + lane];
        float a[8];
        a[0] = bfl(af.x); a[1] = bfh(af.x);
        a[2] = bfl(af.y); a[3] = bfh(af.y);
        a[4] = bfl(af.z); a[5] = bfh(af.z);
        a[6] = bfl(af.w); a[7] = bfh(af.w);

        int pid[2 * WINDOW];
        bool pval[2 * WINDOW];
#pragma unroll
        for (int j = 0; j < 2 * WINDOW; j++) {
            int off = (j < WINDOW) ? (j - WINDOW) : (j - WINDOW + 1);
            int p = l + off;
            pval[j] = (p >= 0 && p < WALK_LEN);
            int pc = p < 0 ? 0 : (p > WALK_LEN - 1 ? WALK_LEN - 1 : p);
            pid[j] = wids[pc];
        }

        float pos_sum = 0.f;
#pragma unroll
        for (int j = 0; j < 2 * WINDOW; j++) {
            if (!pval[j]) continue;                  // wave-uniform branch
            int off = (j < WINDOW) ? (j - WINDOW) : (j - WINDOW + 1);
            int p = l + off;
            float d = dot8(a, s4[p * 64 + lane]);
            for (int o = 32; o > 0; o >>= 1) d += __shfl_xor(d, o, 64);
            pos_sum += expf(d * INV_TEMP);
        }

        const int nbase = (b * WALK_LEN + l) * NEG_S;
        uint4 nf[NEG_S];
        bool nmask[NEG_S];
#pragma unroll
        for (int s = 0; s < NEG_S; s++) {
            int node = negs[nbase + s];
            bool msk = false;
#pragma unroll
            for (int j = 0; j < 2 * WINDOW; j++)
                msk = msk || (pval[j] && pid[j] == node);
            nmask[s] = msk;
            nf[s] = g4[(size_t)node * 64 + lane];
        }
        float neg_sum = 0.f;
#pragma unroll
        for (int s = 0; s < NEG_S; s++) {
            if (nmask[s]) continue;                  // wave-uniform branch
            float d = dot8(a, nf[s]);
            for (int o = 32; o > 0; o >>= 1) d += __shfl_xor(d, o, 64);
            neg_sum += expf(d * INV_TEMP);
        }
        acc_term += logf(1.f + neg_sum / pos_sum);   // pos_sum>0 always
    }
    if (lane == 0) wsum[w] = acc_term;
    __syncthreads();
    if (t == 0) atomicAdd(out, wsum[0] + wsum[1] + wsum[2] + wsum[3]);
}

extern "C" void kernel_launch(void* const* d_in, const int* in_sizes, int n_in,
                              void* d_out, int out_size, void* d_ws, size_t ws_size,
                              hipStream_t stream) {
    const float* x      = (const float*)d_in[0];
    const int*   ei     = (const int*)d_in[1];
    const int*   walks  = (const int*)d_in[2];
    const int*   negs   = (const int*)d_in[3];
    const float* W1     = (const float*)d_in[4];
    const float* a_src1 = (const float*)d_in[5];
    const float* a_dst1 = (const float*)d_in[6];
    const float* b1     = (const float*)d_in[7];
    const float* W2     = (const float*)d_in[8];
    const float* a_src2 = (const float*)d_in[9];
    const float* a_dst2 = (const float*)d_in[10];
    const float* b2     = (const float*)d_in[11];
    float* out = (float*)d_out;

    float* ws = (float*)d_ws;
    size_t off = 0;
    float* region0 = ws + off; off += (size_t)N_NODES * 256;   // xwb (bf16) both layers
    float* emb1  = ws + off; off += (size_t)N_NODES * 256;
    float* region2 = ws + off; off += (size_t)N_NODES * 256;   // embn (separate from xwb!)
    float* als1  = ws + off; off += N_NODES * HEADS_1;
    float* ald1  = ws + off; off += N_NODES * HEADS_1;
    float* als2  = ws + off; off += N_NODES;
    float* ald2  = ws + off; off += N_NODES;
    int* deg       = (int*)(ws + off); off += N_NODES;
    int* excl      = (int*)(ws + off); off += N_NODES;
    int* bsum      = (int*)(ws + off); off += 256;
    int* row_start = (int*)(ws + off); off += N_NODES + 1;
    int* cursor    = (int*)(ws + off); off += N_NODES;
    int* srclist   = (int*)(ws + off); off += E_EDGES;
    unsigned short* xwb = (unsigned short*)region0;  // [N][256] bf16
    uint* embn = (uint*)region2;                     // [N][256] 2-packed bf16

    hipMemsetAsync(out, 0, sizeof(float) * out_size, stream);
    hipMemsetAsync(deg, 0, sizeof(int) * N_NODES, stream);
    hipMemsetAsync(cursor, 0, sizeof(int) * N_NODES, stream);

    // ---- CSR build (shared by both layers) ----
    deg_kernel<<<(E_EDGES + 255) / 256, 256, 0, stream>>>(ei, deg);
    scan_a<<<SCAN_BLOCKS, 256, 0, stream>>>(deg, excl, bsum);
    scan_b<<<1, 256, 0, stream>>>(bsum);
    scan_c2<<<SCAN_BLOCKS, 256, 0, stream>>>(excl, bsum, row_start);
    bucket_kernel<<<(E_EDGES + 255) / 256, 256, 0, stream>>>(ei, row_start, cursor, srclist);

    // ---- layer 1 (heads=8, hid=32) ----
    gemm_rows<128><<<N_NODES / 16, 256, 0, stream>>>(x, W1, xwb);
    al_wave_kernel<HEADS_1><<<(N_NODES * 64 + 255) / 256, 256, 0, stream>>>(
        (const uint*)xwb, a_src1, a_dst1, als1, ald1);
    gat_gather1<<<N_NODES / 4, 256, 0, stream>>>(
        row_start, srclist, als1, ald1, (const uint*)xwb, b1, emb1);

    // ---- layer 2 (heads=1, hid=256), fused normalize+pack ----
    gemm_rows<256><<<N_NODES / 16, 256, 0, stream>>>(emb1, W2, xwb);
    al_wave_kernel<1><<<(N_NODES * 64 + 255) / 256, 256, 0, stream>>>(
        (const uint*)xwb, a_src2, a_dst2, als2, ald2);
    gat_gather2<<<N_NODES / 4, 256, 0, stream>>>(
        row_start, srclist, als2, ald2, (const uint*)xwb, b2, emb1, embn);

    // ---- contrastive loss ----
    loss_walk_kernel<<<NUM_WALKS, 256, 0, stream>>>(embn, walks, negs, out);
}

// Round 6
// 635.562 us; speedup vs baseline: 4.5781x; 1.0959x over previous
//
#include <hip/hip_runtime.h>
#include <math.h>

#define N_NODES 50000
#define E_EDGES 800000
#define FDIM_IN 128
#define HID_1 32
#define HEADS_1 8
#define H1DIM 256
#define NUM_WALKS 512
#define WALK_LEN 64
#define WINDOW 5
#define NEG_S 10
#define TEMP 0.07f
#define INV_TEMP (1.0f / 0.07f)
#define NEG_SLOPE 0.2f

#define SCAN_BLOCKS ((N_NODES + 255) / 256)   // 196

typedef unsigned int uint;

__device__ __forceinline__ float leaky(float v) {
    return v > 0.f ? v : v * NEG_SLOPE;
}

__device__ __forceinline__ float bfl(uint u) { return __uint_as_float(u << 16); }
__device__ __forceinline__ float bfh(uint u) { return __uint_as_float(u & 0xffff0000u); }

__device__ __forceinline__ unsigned short f2bf(float x) {
    uint u = __float_as_uint(x);
    u = u + 0x7fffu + ((u >> 16) & 1u);   // round-to-nearest-even
    return (unsigned short)(u >> 16);
}

// ---------------- CSR build ----------------

__global__ void deg_kernel(const int* __restrict__ ei, int* __restrict__ deg) {
    int e = blockIdx.x * blockDim.x + threadIdx.x;
    if (e < E_EDGES) atomicAdd(&deg[ei[E_EDGES + e]], 1);
}

__global__ __launch_bounds__(256) void scan_a(const int* __restrict__ deg,
                                              int* __restrict__ excl,
                                              int* __restrict__ bsum) {
    __shared__ int s[256];
    int t = threadIdx.x;
    int i = blockIdx.x * 256 + t;
    int v = (i < N_NODES) ? deg[i] : 0;
    s[t] = v;
    __syncthreads();
    for (int off = 1; off < 256; off <<= 1) {
        int tmp = (t >= off) ? s[t - off] : 0;
        __syncthreads();
        s[t] += tmp;
        __syncthreads();
    }
    if (i < N_NODES) excl[i] = s[t] - v;
    if (t == 255) bsum[blockIdx.x] = s[255];
}

__global__ __launch_bounds__(256) void scan_b(int* __restrict__ bsum) {
    __shared__ int s[256];
    int t = threadIdx.x;
    int v = (t < SCAN_BLOCKS) ? bsum[t] : 0;
    s[t] = v;
    __syncthreads();
    for (int off = 1; off < 256; off <<= 1) {
        int tmp = (t >= off) ? s[t - off] : 0;
        __syncthreads();
        s[t] += tmp;
        __syncthreads();
    }
    if (t < SCAN_BLOCKS) bsum[t] = s[t] - v;   // exclusive
}

__global__ void scan_c2(int* __restrict__ excl, const int* __restrict__ bsum,
                        int* __restrict__ row_start) {
    int i = blockIdx.x * blockDim.x + threadIdx.x;
    if (i < N_NODES) row_start[i] = excl[i] + bsum[i >> 8];
    if (i == 0) row_start[N_NODES] = E_EDGES;
}

__global__ void bucket_kernel(const int* __restrict__ ei,
                              const int* __restrict__ row_start,
                              int* __restrict__ cursor,
                              int* __restrict__ srclist) {
    int e = blockIdx.x * blockDim.x + threadIdx.x;
    if (e >= E_EDGES) return;
    int dst = ei[E_EDGES + e];
    int pos = atomicAdd(&cursor[dst], 1);
    srclist[row_start[dst] + pos] = ei[e];
}

// ---------------- dense compute ----------------

// Y[n][j] = sum_k X[n][k]*W[k][j], output packed bf16 (ushort per element)
template<int K>
__global__ __launch_bounds__(256) void gemm_rows(const float* __restrict__ X,
                                                 const float* __restrict__ W,
                                                 unsigned short* __restrict__ Yb) {
    __shared__ float xs[16][K];
    const int row0 = blockIdx.x * 16;
    const int t = threadIdx.x;
    for (int i = t; i < 16 * K; i += 256) {
        int r = i / K, k = i % K;
        xs[r][k] = X[(size_t)(row0 + r) * K + k];
    }
    __syncthreads();
    float acc[16];
#pragma unroll
    for (int r = 0; r < 16; r++) acc[r] = 0.f;
    for (int k = 0; k < K; k++) {
        float w = W[k * 256 + t];
#pragma unroll
        for (int r = 0; r < 16; r++) acc[r] += xs[r][k] * w;
    }
#pragma unroll
    for (int r = 0; r < 16; r++) Yb[(size_t)(row0 + r) * 256 + t] = f2bf(acc[r]);
}

// one wave per node: als/ald from bf16 row, shuffle-reduced per head
template<int H>
__global__ __launch_bounds__(256) void al_wave_kernel(
        const uint* __restrict__ xwb,                    // row stride 128 uints
        const float* __restrict__ a_src, const float* __restrict__ a_dst,
        float* __restrict__ als, float* __restrict__ ald) {
    int wid = (blockIdx.x * 256 + threadIdx.x) >> 6;
    int lane = threadIdx.x & 63;
    if (wid >= N_NODES) return;
    uint2 u = ((const uint2*)(xwb + (size_t)wid * 128))[lane];
    int col = lane * 4;
    float x0 = bfl(u.x), x1 = bfh(u.x), x2 = bfl(u.y), x3 = bfh(u.y);
    float s = x0 * a_src[col] + x1 * a_src[col + 1] + x2 * a_src[col + 2] + x3 * a_src[col + 3];
    float d = x0 * a_dst[col] + x1 * a_dst[col + 1] + x2 * a_dst[col + 2] + x3 * a_dst[col + 3];
#pragma unroll
    for (int o = 32 / H; o > 0; o >>= 1) {
        s += __shfl_xor(s, o, 64);
        d += __shfl_xor(d, o, 64);
    }
    if ((lane & (64 / H - 1)) == 0) {
        int h = lane / (64 / H);
        als[wid * H + h] = s;
        ald[wid * H + h] = d;
    }
}

#define UN 8

// layer-1 gather: wave per node, 8-deep batched edge loads, ELU, fp32 out
__global__ __launch_bounds__(256) void gat_gather1(
        const int* __restrict__ row_start, const int* __restrict__ srclist,
        const float* __restrict__ als, const float* __restrict__ ald,
        const uint* __restrict__ xwb,                    // row stride 128 uints
        const float* __restrict__ bias,
        float* __restrict__ emb1) {
    const int wid = blockIdx.x * 4 + (threadIdx.x >> 6);
    const int lane = threadIdx.x & 63;
    const int h = lane >> 3;                             // head = (4*lane)/32
    const float ald_n = ald[wid * HEADS_1 + h];
    const int beg = row_start[wid], end = row_start[wid + 1];
    const uint2* rowp = (const uint2*)xwb;               // row stride 64 uint2

    float ex0 = __expf(leaky(als[wid * HEADS_1 + h] + ald_n));
    uint2 u = rowp[(size_t)wid * 64 + lane];
    float den = ex0;
    float a0 = ex0 * bfl(u.x), a1 = ex0 * bfh(u.x);
    float a2 = ex0 * bfl(u.y), a3 = ex0 * bfh(u.y);

    for (int i = beg; i < end; i += UN) {
        int ss[UN]; uint2 rr[UN]; float ee[UN];
#pragma unroll
        for (int j = 0; j < UN; j++) ss[j] = srclist[min(i + j, end - 1)];
#pragma unroll
        for (int j = 0; j < UN; j++) rr[j] = rowp[(size_t)ss[j] * 64 + lane];
#pragma unroll
        for (int j = 0; j < UN; j++) ee[j] = als[ss[j] * HEADS_1 + h];
#pragma unroll
        for (int j = 0; j < UN; j++) {
            float ex = (i + j < end) ? __expf(leaky(ee[j] + ald_n)) : 0.f;
            den += ex;
            a0 += ex * bfl(rr[j].x); a1 += ex * bfh(rr[j].x);
            a2 += ex * bfl(rr[j].y); a3 += ex * bfh(rr[j].y);
        }
    }
    float inv = 1.f / den;
    float4 bv = ((const float4*)bias)[lane];
    float4 r;
    r.x = a0 * inv + bv.x; r.y = a1 * inv + bv.y;
    r.z = a2 * inv + bv.z; r.w = a3 * inv + bv.w;
    r.x = r.x > 0.f ? r.x : __expf(r.x) - 1.f;
    r.y = r.y > 0.f ? r.y : __expf(r.y) - 1.f;
    r.z = r.z > 0.f ? r.z : __expf(r.z) - 1.f;
    r.w = r.w > 0.f ? r.w : __expf(r.w) - 1.f;
    ((float4*)emb1)[(size_t)wid * 64 + lane] = r;
}

// layer-2 gather fused with normalize+pack: emb2 never materialized
__global__ __launch_bounds__(256) void gat_gather2(
        const int* __restrict__ row_start, const int* __restrict__ srclist,
        const float* __restrict__ als, const float* __restrict__ ald,
        const uint* __restrict__ xwb,                    // row stride 128 uints
        const float* __restrict__ bias,
        const float* __restrict__ emb1,
        uint* __restrict__ embn) {                       // row stride 256 uints
    const int wid = blockIdx.x * 4 + (threadIdx.x >> 6);
    const int lane = threadIdx.x & 63;
    const float ald_n = ald[wid];
    const int beg = row_start[wid], end = row_start[wid + 1];
    const uint2* rowp = (const uint2*)xwb;

    float ex0 = __expf(leaky(als[wid] + ald_n));
    uint2 u = rowp[(size_t)wid * 64 + lane];
    float den = ex0;
    float a0 = ex0 * bfl(u.x), a1 = ex0 * bfh(u.x);
    float a2 = ex0 * bfl(u.y), a3 = ex0 * bfh(u.y);

    for (int i = beg; i < end; i += UN) {
        int ss[UN]; uint2 rr[UN]; float ee[UN];
#pragma unroll
        for (int j = 0; j < UN; j++) ss[j] = srclist[min(i + j, end - 1)];
#pragma unroll
        for (int j = 0; j < UN; j++) rr[j] = rowp[(size_t)ss[j] * 64 + lane];
#pragma unroll
        for (int j = 0; j < UN; j++) ee[j] = als[ss[j]];
#pragma unroll
        for (int j = 0; j < UN; j++) {
            float ex = (i + j < end) ? __expf(leaky(ee[j] + ald_n)) : 0.f;
            den += ex;
            a0 += ex * bfl(rr[j].x); a1 += ex * bfh(rr[j].x);
            a2 += ex * bfl(rr[j].y); a3 += ex * bfh(rr[j].y);
        }
    }
    float inv = 1.f / den;
    float4 bv = ((const float4*)bias)[lane];
    float4 e2;
    e2.x = a0 * inv + bv.x; e2.y = a1 * inv + bv.y;
    e2.z = a2 * inv + bv.z; e2.w = a3 * inv + bv.w;
    float4 e1 = ((const float4*)emb1)[(size_t)wid * 64 + lane];

    float ssum = e1.x * e1.x + e1.y * e1.y + e1.z * e1.z + e1.w * e1.w
               + e2.x * e2.x + e2.y * e2.y + e2.z * e2.z + e2.w * e2.w;
#pragma unroll
    for (int o = 32; o > 0; o >>= 1) ssum += __shfl_xor(ssum, o, 64);
    float innv = 1.f / fmaxf(sqrtf(ssum), 1e-8f);

    uint2 p1, p2;
    p1.x = (uint)f2bf(e1.x * innv) | ((uint)f2bf(e1.y * innv) << 16);
    p1.y = (uint)f2bf(e1.z * innv) | ((uint)f2bf(e1.w * innv) << 16);
    p2.x = (uint)f2bf(e2.x * innv) | ((uint)f2bf(e2.y * innv) << 16);
    p2.y = (uint)f2bf(e2.z * innv) | ((uint)f2bf(e2.w * innv) << 16);
    ((uint2*)embn)[(size_t)wid * 128 + lane] = p1;        // cols 0..255   (emb1 part)
    ((uint2*)embn)[(size_t)wid * 128 + 64 + lane] = p2;   // cols 256..511 (emb2 part)
}

__device__ __forceinline__ float dot8(const float a[8], uint4 c) {
    float d;
    d  = a[0] * bfl(c.x) + a[1] * bfh(c.x);
    d += a[2] * bfl(c.y) + a[3] * bfh(c.y);
    d += a[4] * bfl(c.z) + a[5] * bfh(c.z);
    d += a[6] * bfl(c.w) + a[7] * bfh(c.w);
    return d;
}

#define ANCH 16                         // anchors per block (walk segment)
#define MAXROWS (ANCH + 2 * WINDOW)     // 26 LDS rows max

// one block per walk-segment of 16 anchors; pos rows in LDS; negs streamed
__global__ __launch_bounds__(256) void loss_seg_kernel(
        const uint* __restrict__ embn,     // 2-packed bf16, row stride 256 uints
        const int* __restrict__ walks, const int* __restrict__ negs,
        float* __restrict__ out) {
    __shared__ __align__(16) uint srows[MAXROWS * 256];   // 26 KB
    __shared__ int wids[MAXROWS];
    __shared__ float wsum[4];
    const int blk = blockIdx.x;
    const int b = blk >> 2;                  // walk
    const int l0 = (blk & 3) * ANCH;         // first anchor of segment
    const int base = max(0, l0 - WINDOW);
    const int hi = min(WALK_LEN - 1, l0 + ANCH - 1 + WINDOW);
    const int cnt = hi - base + 1;           // 21..26
    const int t = threadIdx.x;
    const int w = t >> 6, lane = t & 63;
    if (t < cnt) wids[t] = walks[b * WALK_LEN + base + t];
    __syncthreads();
    const uint4* g4 = (const uint4*)embn;    // row stride 64 uint4
    uint4* s4 = (uint4*)srows;
    for (int r = w; r < cnt; r += 4)
        s4[r * 64 + lane] = g4[(size_t)wids[r] * 64 + lane];
    __syncthreads();

    float acc_term = 0.f;
#pragma unroll
    for (int k = 0; k < ANCH / 4; k++) {
        const int l = l0 + w + 4 * k;        // this wave's anchor
        uint4 af = s4[(l - base) * 64 + lane];
        float a[8];
        a[0] = bfl(af.x); a[1] = bfh(af.x);
        a[2] = bfl(af.y); a[3] = bfh(af.y);
        a[4] = bfl(af.z); a[5] = bfh(af.z);
        a[6] = bfl(af.w); a[7] = bfh(af.w);

        int pid[2 * WINDOW];
        bool pval[2 * WINDOW];
        int prow[2 * WINDOW];
#pragma unroll
        for (int j = 0; j < 2 * WINDOW; j++) {
            int off = (j < WINDOW) ? (j - WINDOW) : (j - WINDOW + 1);
            int p = l + off;
            pval[j] = (p >= 0 && p < WALK_LEN);
            int pc = p < 0 ? 0 : (p > WALK_LEN - 1 ? WALK_LEN - 1 : p);
            prow[j] = pc - base;
            pid[j] = wids[pc - base];
        }

        float pos_sum = 0.f;
#pragma unroll
        for (int j = 0; j < 2 * WINDOW; j++) {
            if (!pval[j]) continue;              // wave-uniform branch
            float d = dot8(a, s4[prow[j] * 64 + lane]);
            for (int o = 32; o > 0; o >>= 1) d += __shfl_xor(d, o, 64);
            pos_sum += expf(d * INV_TEMP);
        }

        const int nbase = (b * WALK_LEN + l) * NEG_S;
        uint4 nf[NEG_S];
        bool nmask[NEG_S];
#pragma unroll
        for (int s = 0; s < NEG_S; s++) {
            int node = negs[nbase + s];
            bool msk = false;
#pragma unroll
            for (int j = 0; j < 2 * WINDOW; j++)
                msk = msk || (pval[j] && pid[j] == node);
            nmask[s] = msk;
            nf[s] = g4[(size_t)node * 64 + lane];
        }
        float neg_sum = 0.f;
#pragma unroll
        for (int s = 0; s < NEG_S; s++) {
            if (nmask[s]) continue;              // wave-uniform branch
            float d = dot8(a, nf[s]);
            for (int o = 32; o > 0; o >>= 1) d += __shfl_xor(d, o, 64);
            neg_sum += expf(d * INV_TEMP);
        }
        acc_term += logf(1.f + neg_sum / pos_sum);   // pos_sum>0 always
    }
    if (lane == 0) wsum[w] = acc_term;
    __syncthreads();
    if (t == 0) atomicAdd(out, wsum[0] + wsum[1] + wsum[2] + wsum[3]);
}

extern "C" void kernel_launch(void* const* d_in, const int* in_sizes, int n_in,
                              void* d_out, int out_size, void* d_ws, size_t ws_size,
                              hipStream_t stream) {
    const float* x      = (const float*)d_in[0];
    const int*   ei     = (const int*)d_in[1];
    const int*   walks  = (const int*)d_in[2];
    const int*   negs   = (const int*)d_in[3];
    const float* W1     = (const float*)d_in[4];
    const float* a_src1 = (const float*)d_in[5];
    const float* a_dst1 = (const float*)d_in[6];
    const float* b1     = (const float*)d_in[7];
    const float* W2     = (const float*)d_in[8];
    const float* a_src2 = (const float*)d_in[9];
    const float* a_dst2 = (const float*)d_in[10];
    const float* b2     = (const float*)d_in[11];
    float* out = (float*)d_out;

    float* ws = (float*)d_ws;
    size_t off = 0;
    float* region0 = ws + off; off += (size_t)N_NODES * 256;   // xwb (bf16) both layers
    float* emb1  = ws + off; off += (size_t)N_NODES * 256;
    float* region2 = ws + off; off += (size_t)N_NODES * 256;   // embn (separate from xwb!)
    float* als1  = ws + off; off += N_NODES * HEADS_1;
    float* ald1  = ws + off; off += N_NODES * HEADS_1;
    float* als2  = ws + off; off += N_NODES;
    float* ald2  = ws + off; off += N_NODES;
    int* deg       = (int*)(ws + off); off += N_NODES;
    int* excl      = (int*)(ws + off); off += N_NODES;
    int* bsum      = (int*)(ws + off); off += 256;
    int* row_start = (int*)(ws + off); off += N_NODES + 1;
    int* cursor    = (int*)(ws + off); off += N_NODES;
    int* srclist   = (int*)(ws + off); off += E_EDGES;
    unsigned short* xwb = (unsigned short*)region0;  // [N][256] bf16
    uint* embn = (uint*)region2;                     // [N][256] 2-packed bf16

    hipMemsetAsync(out, 0, sizeof(float) * out_size, stream);
    hipMemsetAsync(deg, 0, sizeof(int) * N_NODES, stream);
    hipMemsetAsync(cursor, 0, sizeof(int) * N_NODES, stream);

    // ---- CSR build (shared by both layers) ----
    deg_kernel<<<(E_EDGES + 255) / 256, 256, 0, stream>>>(ei, deg);
    scan_a<<<SCAN_BLOCKS, 256, 0, stream>>>(deg, excl, bsum);
    scan_b<<<1, 256, 0, stream>>>(bsum);
    scan_c2<<<SCAN_BLOCKS, 256, 0, stream>>>(excl, bsum, row_start);
    bucket_kernel<<<(E_EDGES + 255) / 256, 256, 0, stream>>>(ei, row_start, cursor, srclist);

    // ---- layer 1 (heads=8, hid=32) ----
    gemm_rows<128><<<N_NODES / 16, 256, 0, stream>>>(x, W1, xwb);
    al_wave_kernel<HEADS_1><<<(N_NODES * 64 + 255) / 256, 256, 0, stream>>>(
        (const uint*)xwb, a_src1, a_dst1, als1, ald1);
    gat_gather1<<<N_NODES / 4, 256, 0, stream>>>(
        row_start, srclist, als1, ald1, (const uint*)xwb, b1, emb1);

    // ---- layer 2 (heads=1, hid=256), fused normalize+pack ----
    gemm_rows<256><<<N_NODES / 16, 256, 0, stream>>>(emb1, W2, xwb);
    al_wave_kernel<1><<<(N_NODES * 64 + 255) / 256, 256, 0, stream>>>(
        (const uint*)xwb, a_src2, a_dst2, als2, ald2);
    gat_gather2<<<N_NODES / 4, 256, 0, stream>>>(
        row_start, srclist, als2, ald2, (const uint*)xwb, b2, emb1, embn);

    // ---- contrastive loss ----
    loss_seg_kernel<<<NUM_WALKS * 4, 256, 0, stream>>>(embn, walks, negs, out);
}

// Round 7
// 527.109 us; speedup vs baseline: 5.5201x; 1.2057x over previous
//
#include <hip/hip_runtime.h>
#include <math.h>

#define N_NODES 50000
#define E_EDGES 800000
#define FDIM_IN 128
#define HID_1 32
#define HEADS_1 8
#define H1DIM 256
#define NUM_WALKS 512
#define WALK_LEN 64
#define WINDOW 5
#define NEG_S 10
#define TEMP 0.07f
#define INV_TEMP (1.0f / 0.07f)
#define NEG_SLOPE 0.2f

#define SCAN_BLOCKS ((N_NODES + 255) / 256)   // 196

typedef unsigned int uint;
typedef unsigned short ushort;
typedef __attribute__((ext_vector_type(8))) short bf16x8;
typedef __attribute__((ext_vector_type(4))) float f32x4;

__device__ __forceinline__ float leaky(float v) {
    return v > 0.f ? v : v * NEG_SLOPE;
}

__device__ __forceinline__ float bfl(uint u) { return __uint_as_float(u << 16); }
__device__ __forceinline__ float bfh(uint u) { return __uint_as_float(u & 0xffff0000u); }

__device__ __forceinline__ ushort f2bf(float x) {
    uint u = __float_as_uint(x);
    u = u + 0x7fffu + ((u >> 16) & 1u);   // round-to-nearest-even
    return (ushort)(u >> 16);
}

// ---------------- CSR build ----------------

__global__ void deg_kernel(const int* __restrict__ ei, int* __restrict__ deg) {
    int e = blockIdx.x * blockDim.x + threadIdx.x;
    if (e < E_EDGES) atomicAdd(&deg[ei[E_EDGES + e]], 1);
}

__global__ __launch_bounds__(256) void scan_a(const int* __restrict__ deg,
                                              int* __restrict__ excl,
                                              int* __restrict__ bsum) {
    __shared__ int s[256];
    int t = threadIdx.x;
    int i = blockIdx.x * 256 + t;
    int v = (i < N_NODES) ? deg[i] : 0;
    s[t] = v;
    __syncthreads();
    for (int off = 1; off < 256; off <<= 1) {
        int tmp = (t >= off) ? s[t - off] : 0;
        __syncthreads();
        s[t] += tmp;
        __syncthreads();
    }
    if (i < N_NODES) excl[i] = s[t] - v;
    if (t == 255) bsum[blockIdx.x] = s[255];
}

__global__ __launch_bounds__(256) void scan_b(int* __restrict__ bsum) {
    __shared__ int s[256];
    int t = threadIdx.x;
    int v = (t < SCAN_BLOCKS) ? bsum[t] : 0;
    s[t] = v;
    __syncthreads();
    for (int off = 1; off < 256; off <<= 1) {
        int tmp = (t >= off) ? s[t - off] : 0;
        __syncthreads();
        s[t] += tmp;
        __syncthreads();
    }
    if (t < SCAN_BLOCKS) bsum[t] = s[t] - v;   // exclusive
}

__global__ void scan_c2(int* __restrict__ excl, const int* __restrict__ bsum,
                        int* __restrict__ row_start) {
    int i = blockIdx.x * blockDim.x + threadIdx.x;
    if (i < N_NODES) row_start[i] = excl[i] + bsum[i >> 8];
    if (i == 0) row_start[N_NODES] = E_EDGES;
}

__global__ void bucket_kernel(const int* __restrict__ ei,
                              const int* __restrict__ row_start,
                              int* __restrict__ cursor,
                              int* __restrict__ srclist) {
    int e = blockIdx.x * blockDim.x + threadIdx.x;
    if (e >= E_EDGES) return;
    int dst = ei[E_EDGES + e];
    int pos = atomicAdd(&cursor[dst], 1);
    srclist[row_start[dst] + pos] = ei[e];
}

// ---------------- dtype conversion ----------------

// 4 floats -> 2 packed-bf16 uints per thread
__global__ void f32_to_bf16_kernel(const float* __restrict__ src, uint* __restrict__ dst, int n4) {
    int i = blockIdx.x * blockDim.x + threadIdx.x;
    if (i >= n4) return;
    float4 v = ((const float4*)src)[i];
    uint2 p;
    p.x = (uint)f2bf(v.x) | ((uint)f2bf(v.y) << 16);
    p.y = (uint)f2bf(v.z) | ((uint)f2bf(v.w) << 16);
    ((uint2*)dst)[i] = p;
}

// W[K][256] fp32 -> Wt[256][K] bf16
__global__ void wtrans_kernel(const float* __restrict__ W, ushort* __restrict__ Wt, int K) {
    int tid = blockIdx.x * blockDim.x + threadIdx.x;
    if (tid >= 256 * K) return;
    int k = tid >> 8, n = tid & 255;
    Wt[n * K + k] = f2bf(W[k * 256 + n]);
}

// ---------------- MFMA GEMM: Y[M][256] = A[M][K] * W[K][256], all bf16 ----------------
// block = 16 rows; 4 waves, wave w owns cols 64w..64w+63 (4 16x16 tiles)
template<int K>
__global__ __launch_bounds__(256) void mfma_gemm(
        const ushort* __restrict__ A,    // [M][K] bf16
        const ushort* __restrict__ Wt,   // [256][K] bf16 (transposed)
        ushort* __restrict__ Y) {        // [M][256] bf16
    constexpr int KP = K + 8;            // +8 ushort pad: bank-conflict-free ds_read_b128
    constexpr int K8 = K / 8;
    __shared__ ushort As[16 * KP];
    const int m0 = blockIdx.x * 16;
    const int t = threadIdx.x;
    const uint4* Ag = (const uint4*)(A + (size_t)m0 * K);
    uint4* As4 = (uint4*)As;
    for (int i = t; i < 16 * K8; i += 256) {
        int r = i / K8, c8 = i % K8;
        As4[r * (K8 + 1) + c8] = Ag[i];
    }
    __syncthreads();
    const int wv = t >> 6, lane = t & 63;
    const int n0 = wv * 64;
    const int mrow = lane & 15, q = lane >> 4;
    f32x4 acc[4];
#pragma unroll
    for (int i = 0; i < 4; i++) acc[i] = (f32x4){0.f, 0.f, 0.f, 0.f};
    const ushort* arow = As + mrow * KP + q * 8;
#pragma unroll
    for (int k0 = 0; k0 < K; k0 += 32) {
        bf16x8 a = *(const bf16x8*)(arow + k0);
#pragma unroll
        for (int i = 0; i < 4; i++) {
            bf16x8 b = *(const bf16x8*)(Wt + (size_t)(n0 + i * 16 + mrow) * K + k0 + q * 8);
            acc[i] = __builtin_amdgcn_mfma_f32_16x16x32_bf16(a, b, acc[i], 0, 0, 0);
        }
    }
#pragma unroll
    for (int i = 0; i < 4; i++)
#pragma unroll
        for (int r = 0; r < 4; r++)
            Y[(size_t)(m0 + q * 4 + r) * 256 + n0 + i * 16 + mrow] = f2bf(acc[i][r]);
}

// ---------------- attention logits ----------------

// one wave per node: als/ald from bf16 row, shuffle-reduced per head
template<int H>
__global__ __launch_bounds__(256) void al_wave_kernel(
        const uint* __restrict__ xwb,                    // row stride 128 uints
        const float* __restrict__ a_src, const float* __restrict__ a_dst,
        float* __restrict__ als, float* __restrict__ ald) {
    int wid = (blockIdx.x * 256 + threadIdx.x) >> 6;
    int lane = threadIdx.x & 63;
    if (wid >= N_NODES) return;
    uint2 u = ((const uint2*)(xwb + (size_t)wid * 128))[lane];
    int col = lane * 4;
    float x0 = bfl(u.x), x1 = bfh(u.x), x2 = bfl(u.y), x3 = bfh(u.y);
    float s = x0 * a_src[col] + x1 * a_src[col + 1] + x2 * a_src[col + 2] + x3 * a_src[col + 3];
    float d = x0 * a_dst[col] + x1 * a_dst[col + 1] + x2 * a_dst[col + 2] + x3 * a_dst[col + 3];
#pragma unroll
    for (int o = 32 / H; o > 0; o >>= 1) {
        s += __shfl_xor(s, o, 64);
        d += __shfl_xor(d, o, 64);
    }
    if ((lane & (64 / H - 1)) == 0) {
        int h = lane / (64 / H);
        als[wid * H + h] = s;
        ald[wid * H + h] = d;
    }
}

#define UN 8

// layer-1 gather: wave per node, 8-deep batched edge loads, ELU, bf16-packed out
__global__ __launch_bounds__(256) void gat_gather1(
        const int* __restrict__ row_start, const int* __restrict__ srclist,
        const float* __restrict__ als, const float* __restrict__ ald,
        const uint* __restrict__ xwb,                    // row stride 128 uints
        const float* __restrict__ bias,
        ushort* __restrict__ emb1b) {                    // [N][256] bf16
    const int wid = blockIdx.x * 4 + (threadIdx.x >> 6);
    const int lane = threadIdx.x & 63;
    const int h = lane >> 3;                             // head = (4*lane)/32
    const float ald_n = ald[wid * HEADS_1 + h];
    const int beg = row_start[wid], end = row_start[wid + 1];
    const uint2* rowp = (const uint2*)xwb;               // row stride 64 uint2

    float ex0 = __expf(leaky(als[wid * HEADS_1 + h] + ald_n));
    uint2 u = rowp[(size_t)wid * 64 + lane];
    float den = ex0;
    float a0 = ex0 * bfl(u.x), a1 = ex0 * bfh(u.x);
    float a2 = ex0 * bfl(u.y), a3 = ex0 * bfh(u.y);

    for (int i = beg; i < end; i += UN) {
        int ss[UN]; uint2 rr[UN]; float ee[UN];
#pragma unroll
        for (int j = 0; j < UN; j++) ss[j] = srclist[min(i + j, end - 1)];
#pragma unroll
        for (int j = 0; j < UN; j++) rr[j] = rowp[(size_t)ss[j] * 64 + lane];
#pragma unroll
        for (int j = 0; j < UN; j++) ee[j] = als[ss[j] * HEADS_1 + h];
#pragma unroll
        for (int j = 0; j < UN; j++) {
            float ex = (i + j < end) ? __expf(leaky(ee[j] + ald_n)) : 0.f;
            den += ex;
            a0 += ex * bfl(rr[j].x); a1 += ex * bfh(rr[j].x);
            a2 += ex * bfl(rr[j].y); a3 += ex * bfh(rr[j].y);
        }
    }
    float inv = 1.f / den;
    float4 bv = ((const float4*)bias)[lane];
    float4 r;
    r.x = a0 * inv + bv.x; r.y = a1 * inv + bv.y;
    r.z = a2 * inv + bv.z; r.w = a3 * inv + bv.w;
    r.x = r.x > 0.f ? r.x : __expf(r.x) - 1.f;
    r.y = r.y > 0.f ? r.y : __expf(r.y) - 1.f;
    r.z = r.z > 0.f ? r.z : __expf(r.z) - 1.f;
    r.w = r.w > 0.f ? r.w : __expf(r.w) - 1.f;
    uint2 p;
    p.x = (uint)f2bf(r.x) | ((uint)f2bf(r.y) << 16);
    p.y = (uint)f2bf(r.z) | ((uint)f2bf(r.w) << 16);
    ((uint2*)emb1b)[(size_t)wid * 64 + lane] = p;
}

// layer-2 gather fused with normalize+pack: emb2 never materialized
__global__ __launch_bounds__(256) void gat_gather2(
        const int* __restrict__ row_start, const int* __restrict__ srclist,
        const float* __restrict__ als, const float* __restrict__ ald,
        const uint* __restrict__ xwb,                    // row stride 128 uints
        const float* __restrict__ bias,
        const ushort* __restrict__ emb1b,                // [N][256] bf16
        uint* __restrict__ embn) {                       // row stride 256 uints
    const int wid = blockIdx.x * 4 + (threadIdx.x >> 6);
    const int lane = threadIdx.x & 63;
    const float ald_n = ald[wid];
    const int beg = row_start[wid], end = row_start[wid + 1];
    const uint2* rowp = (const uint2*)xwb;

    float ex0 = __expf(leaky(als[wid] + ald_n));
    uint2 u = rowp[(size_t)wid * 64 + lane];
    float den = ex0;
    float a0 = ex0 * bfl(u.x), a1 = ex0 * bfh(u.x);
    float a2 = ex0 * bfl(u.y), a3 = ex0 * bfh(u.y);

    for (int i = beg; i < end; i += UN) {
        int ss[UN]; uint2 rr[UN]; float ee[UN];
#pragma unroll
        for (int j = 0; j < UN; j++) ss[j] = srclist[min(i + j, end - 1)];
#pragma unroll
        for (int j = 0; j < UN; j++) rr[j] = rowp[(size_t)ss[j] * 64 + lane];
#pragma unroll
        for (int j = 0; j < UN; j++) ee[j] = als[ss[j]];
#pragma unroll
        for (int j = 0; j < UN; j++) {
            float ex = (i + j < end) ? __expf(leaky(ee[j] + ald_n)) : 0.f;
            den += ex;
            a0 += ex * bfl(rr[j].x); a1 += ex * bfh(rr[j].x);
            a2 += ex * bfl(rr[j].y); a3 += ex * bfh(rr[j].y);
        }
    }
    float inv = 1.f / den;
    float4 bv = ((const float4*)bias)[lane];
    float4 e2;
    e2.x = a0 * inv + bv.x; e2.y = a1 * inv + bv.y;
    e2.z = a2 * inv + bv.z; e2.w = a3 * inv + bv.w;
    uint2 u1 = ((const uint2*)emb1b)[(size_t)wid * 64 + lane];
    float4 e1;
    e1.x = bfl(u1.x); e1.y = bfh(u1.x); e1.z = bfl(u1.y); e1.w = bfh(u1.y);

    float ssum = e1.x * e1.x + e1.y * e1.y + e1.z * e1.z + e1.w * e1.w
               + e2.x * e2.x + e2.y * e2.y + e2.z * e2.z + e2.w * e2.w;
#pragma unroll
    for (int o = 32; o > 0; o >>= 1) ssum += __shfl_xor(ssum, o, 64);
    float innv = 1.f / fmaxf(sqrtf(ssum), 1e-8f);

    uint2 p1, p2;
    p1.x = (uint)f2bf(e1.x * innv) | ((uint)f2bf(e1.y * innv) << 16);
    p1.y = (uint)f2bf(e1.z * innv) | ((uint)f2bf(e1.w * innv) << 16);
    p2.x = (uint)f2bf(e2.x * innv) | ((uint)f2bf(e2.y * innv) << 16);
    p2.y = (uint)f2bf(e2.z * innv) | ((uint)f2bf(e2.w * innv) << 16);
    ((uint2*)embn)[(size_t)wid * 128 + lane] = p1;        // cols 0..255   (emb1 part)
    ((uint2*)embn)[(size_t)wid * 128 + 64 + lane] = p2;   // cols 256..511 (emb2 part)
}

__device__ __forceinline__ float dot8(const float a[8], uint4 c) {
    float d;
    d  = a[0] * bfl(c.x) + a[1] * bfh(c.x);
    d += a[2] * bfl(c.y) + a[3] * bfh(c.y);
    d += a[4] * bfl(c.z) + a[5] * bfh(c.z);
    d += a[6] * bfl(c.w) + a[7] * bfh(c.w);
    return d;
}

#define ANCH 16                         // anchors per block (walk segment)
#define MAXROWS (ANCH + 2 * WINDOW)     // 26 LDS rows max

// one block per walk-segment of 16 anchors; pos rows in LDS; negs streamed
__global__ __launch_bounds__(256) void loss_seg_kernel(
        const uint* __restrict__ embn,     // 2-packed bf16, row stride 256 uints
        const int* __restrict__ walks, const int* __restrict__ negs,
        float* __restrict__ out) {
    __shared__ __align__(16) uint srows[MAXROWS * 256];   // 26 KB
    __shared__ int wids[MAXROWS];
    __shared__ float wsum[4];
    const int blk = blockIdx.x;
    const int b = blk >> 2;                  // walk
    const int l0 = (blk & 3) * ANCH;         // first anchor of segment
    const int base = max(0, l0 - WINDOW);
    const int hi = min(WALK_LEN - 1, l0 + ANCH - 1 + WINDOW);
    const int cnt = hi - base + 1;           // 21..26
    const int t = threadIdx.x;
    const int w = t >> 6, lane = t & 63;
    if (t < cnt) wids[t] = walks[b * WALK_LEN + base + t];
    __syncthreads();
    const uint4* g4 = (const uint4*)embn;    // row stride 64 uint4
    uint4* s4 = (uint4*)srows;
    for (int r = w; r < cnt; r += 4)
        s4[r * 64 + lane] = g4[(size_t)wids[r] * 64 + lane];
    __syncthreads();

    float acc_term = 0.f;
#pragma unroll
    for (int k = 0; k < ANCH / 4; k++) {
        const int l = l0 + w + 4 * k;        // this wave's anchor
        uint4 af = s4[(l - base) * 64 + lane];
        float a[8];
        a[0] = bfl(af.x); a[1] = bfh(af.x);
        a[2] = bfl(af.y); a[3] = bfh(af.y);
        a[4] = bfl(af.z); a[5] = bfh(af.z);
        a[6] = bfl(af.w); a[7] = bfh(af.w);

        int pid[2 * WINDOW];
        bool pval[2 * WINDOW];
        int prow[2 * WINDOW];
#pragma unroll
        for (int j = 0; j < 2 * WINDOW; j++) {
            int off = (j < WINDOW) ? (j - WINDOW) : (j - WINDOW + 1);
            int p = l + off;
            pval[j] = (p >= 0 && p < WALK_LEN);
            int pc = p < 0 ? 0 : (p > WALK_LEN - 1 ? WALK_LEN - 1 : p);
            prow[j] = pc - base;
            pid[j] = wids[pc - base];
        }

        float pos_sum = 0.f;
#pragma unroll
        for (int j = 0; j < 2 * WINDOW; j++) {
            if (!pval[j]) continue;              // wave-uniform branch
            float d = dot8(a, s4[prow[j] * 64 + lane]);
            for (int o = 32; o > 0; o >>= 1) d += __shfl_xor(d, o, 64);
            pos_sum += expf(d * INV_TEMP);
        }

        const int nbase = (b * WALK_LEN + l) * NEG_S;
        uint4 nf[NEG_S];
        bool nmask[NEG_S];
#pragma unroll
        for (int s = 0; s < NEG_S; s++) {
            int node = negs[nbase + s];
            bool msk = false;
#pragma unroll
            for (int j = 0; j < 2 * WINDOW; j++)
                msk = msk || (pval[j] && pid[j] == node);
            nmask[s] = msk;
            nf[s] = g4[(size_t)node * 64 + lane];
        }
        float neg_sum = 0.f;
#pragma unroll
        for (int s = 0; s < NEG_S; s++) {
            if (nmask[s]) continue;              // wave-uniform branch
            float d = dot8(a, nf[s]);
            for (int o = 32; o > 0; o >>= 1) d += __shfl_xor(d, o, 64);
            neg_sum += expf(d * INV_TEMP);
        }
        acc_term += logf(1.f + neg_sum / pos_sum);   // pos_sum>0 always
    }
    if (lane == 0) wsum[w] = acc_term;
    __syncthreads();
    if (t == 0) atomicAdd(out, wsum[0] + wsum[1] + wsum[2] + wsum[3]);
}

extern "C" void kernel_launch(void* const* d_in, const int* in_sizes, int n_in,
                              void* d_out, int out_size, void* d_ws, size_t ws_size,
                              hipStream_t stream) {
    const float* x      = (const float*)d_in[0];
    const int*   ei     = (const int*)d_in[1];
    const int*   walks  = (const int*)d_in[2];
    const int*   negs   = (const int*)d_in[3];
    const float* W1     = (const float*)d_in[4];
    const float* a_src1 = (const float*)d_in[5];
    const float* a_dst1 = (const float*)d_in[6];
    const float* b1     = (const float*)d_in[7];
    const float* W2     = (const float*)d_in[8];
    const float* a_src2 = (const float*)d_in[9];
    const float* a_dst2 = (const float*)d_in[10];
    const float* b2     = (const float*)d_in[11];
    float* out = (float*)d_out;

    float* ws = (float*)d_ws;
    size_t off = 0;
    float* r_xwb   = ws + off; off += (size_t)N_NODES * 128;   // [N][256] bf16
    float* r_emb1b = ws + off; off += (size_t)N_NODES * 128;   // [N][256] bf16
    float* r_embn  = ws + off; off += (size_t)N_NODES * 256;   // [N][512] bf16 (2-packed)
    float* r_xb    = ws + off; off += (size_t)N_NODES * 64;    // [N][128] bf16
    float* r_wt1   = ws + off; off += 256 * 64;                // [256][128] bf16
    float* r_wt2   = ws + off; off += 256 * 128;               // [256][256] bf16
    float* als1  = ws + off; off += N_NODES * HEADS_1;
    float* ald1  = ws + off; off += N_NODES * HEADS_1;
    float* als2  = ws + off; off += N_NODES;
    float* ald2  = ws + off; off += N_NODES;
    int* deg       = (int*)(ws + off); off += N_NODES;
    int* excl      = (int*)(ws + off); off += N_NODES;
    int* bsum      = (int*)(ws + off); off += 256;
    int* row_start = (int*)(ws + off); off += N_NODES + 1;
    int* cursor    = (int*)(ws + off); off += N_NODES;
    int* srclist   = (int*)(ws + off); off += E_EDGES;
    ushort* xwb   = (ushort*)r_xwb;
    ushort* emb1b = (ushort*)r_emb1b;
    uint*   embn  = (uint*)r_embn;
    ushort* xb    = (ushort*)r_xb;
    ushort* wt1   = (ushort*)r_wt1;
    ushort* wt2   = (ushort*)r_wt2;

    hipMemsetAsync(out, 0, sizeof(float) * out_size, stream);
    hipMemsetAsync(deg, 0, sizeof(int) * N_NODES, stream);
    hipMemsetAsync(cursor, 0, sizeof(int) * N_NODES, stream);

    // ---- CSR build (shared by both layers) ----
    deg_kernel<<<(E_EDGES + 255) / 256, 256, 0, stream>>>(ei, deg);
    scan_a<<<SCAN_BLOCKS, 256, 0, stream>>>(deg, excl, bsum);
    scan_b<<<1, 256, 0, stream>>>(bsum);
    scan_c2<<<SCAN_BLOCKS, 256, 0, stream>>>(excl, bsum, row_start);
    bucket_kernel<<<(E_EDGES + 255) / 256, 256, 0, stream>>>(ei, row_start, cursor, srclist);

    // ---- bf16 conversions ----
    f32_to_bf16_kernel<<<(N_NODES * FDIM_IN / 4 + 255) / 256, 256, 0, stream>>>(
        x, (uint*)xb, N_NODES * FDIM_IN / 4);
    wtrans_kernel<<<(256 * 128 + 255) / 256, 256, 0, stream>>>(W1, wt1, 128);
    wtrans_kernel<<<(256 * 256 + 255) / 256, 256, 0, stream>>>(W2, wt2, 256);

    // ---- layer 1 (heads=8, hid=32) ----
    mfma_gemm<128><<<N_NODES / 16, 256, 0, stream>>>(xb, wt1, xwb);
    al_wave_kernel<HEADS_1><<<(N_NODES * 64 + 255) / 256, 256, 0, stream>>>(
        (const uint*)xwb, a_src1, a_dst1, als1, ald1);
    gat_gather1<<<N_NODES / 4, 256, 0, stream>>>(
        row_start, srclist, als1, ald1, (const uint*)xwb, b1, emb1b);

    // ---- layer 2 (heads=1, hid=256), fused normalize+pack ----
    mfma_gemm<256><<<N_NODES / 16, 256, 0, stream>>>(emb1b, wt2, xwb);
    al_wave_kernel<1><<<(N_NODES * 64 + 255) / 256, 256, 0, stream>>>(
        (const uint*)xwb, a_src2, a_dst2, als2, ald2);
    gat_gather2<<<N_NODES / 4, 256, 0, stream>>>(
        row_start, srclist, als2, ald2, (const uint*)xwb, b2, emb1b, embn);

    // ---- contrastive loss ----
    loss_seg_kernel<<<NUM_WALKS * 4, 256, 0, stream>>>(embn, walks, negs, out);
}

// Round 8
// 497.289 us; speedup vs baseline: 5.8511x; 1.0600x over previous
//
#include <hip/hip_runtime.h>
#include <math.h>

#define N_NODES 50000
#define E_EDGES 800000
#define FDIM_IN 128
#define HID_1 32
#define HEADS_1 8
#define H1DIM 256
#define NUM_WALKS 512
#define WALK_LEN 64
#define WINDOW 5
#define NEG_S 10
#define TEMP 0.07f
#define INV_TEMP (1.0f / 0.07f)
#define NEG_SLOPE 0.2f

#define SCAN_BLOCKS ((N_NODES + 255) / 256)   // 196

typedef unsigned int uint;
typedef unsigned short ushort;
typedef __attribute__((ext_vector_type(8))) short bf16x8;
typedef __attribute__((ext_vector_type(4))) float f32x4;

__device__ __forceinline__ float leaky(float v) {
    return v > 0.f ? v : v * NEG_SLOPE;
}

__device__ __forceinline__ float bfl(uint u) { return __uint_as_float(u << 16); }
__device__ __forceinline__ float bfh(uint u) { return __uint_as_float(u & 0xffff0000u); }

__device__ __forceinline__ ushort f2bf(float x) {
    uint u = __float_as_uint(x);
    u = u + 0x7fffu + ((u >> 16) & 1u);   // round-to-nearest-even
    return (ushort)(u >> 16);
}

// ---------------- CSR build ----------------

__global__ void deg_kernel(const int* __restrict__ ei, int* __restrict__ deg) {
    int e = blockIdx.x * blockDim.x + threadIdx.x;
    if (e < E_EDGES) atomicAdd(&deg[ei[E_EDGES + e]], 1);
}

__global__ __launch_bounds__(256) void scan_a(const int* __restrict__ deg,
                                              int* __restrict__ excl,
                                              int* __restrict__ bsum) {
    __shared__ int s[256];
    int t = threadIdx.x;
    int i = blockIdx.x * 256 + t;
    int v = (i < N_NODES) ? deg[i] : 0;
    s[t] = v;
    __syncthreads();
    for (int off = 1; off < 256; off <<= 1) {
        int tmp = (t >= off) ? s[t - off] : 0;
        __syncthreads();
        s[t] += tmp;
        __syncthreads();
    }
    if (i < N_NODES) excl[i] = s[t] - v;
    if (t == 255) bsum[blockIdx.x] = s[255];
}

__global__ __launch_bounds__(256) void scan_b(int* __restrict__ bsum) {
    __shared__ int s[256];
    int t = threadIdx.x;
    int v = (t < SCAN_BLOCKS) ? bsum[t] : 0;
    s[t] = v;
    __syncthreads();
    for (int off = 1; off < 256; off <<= 1) {
        int tmp = (t >= off) ? s[t - off] : 0;
        __syncthreads();
        s[t] += tmp;
        __syncthreads();
    }
    if (t < SCAN_BLOCKS) bsum[t] = s[t] - v;   // exclusive
}

__global__ void scan_c2(int* __restrict__ excl, const int* __restrict__ bsum,
                        int* __restrict__ row_start) {
    int i = blockIdx.x * blockDim.x + threadIdx.x;
    if (i < N_NODES) row_start[i] = excl[i] + bsum[i >> 8];
    if (i == 0) row_start[N_NODES] = E_EDGES;
}

__global__ void bucket_kernel(const int* __restrict__ ei,
                              const int* __restrict__ row_start,
                              int* __restrict__ cursor,
                              int* __restrict__ srclist) {
    int e = blockIdx.x * blockDim.x + threadIdx.x;
    if (e >= E_EDGES) return;
    int dst = ei[E_EDGES + e];
    int pos = atomicAdd(&cursor[dst], 1);
    srclist[row_start[dst] + pos] = ei[e];
}

// ---------------- dtype conversion ----------------

__global__ void f32_to_bf16_kernel(const float* __restrict__ src, uint* __restrict__ dst, int n4) {
    int i = blockIdx.x * blockDim.x + threadIdx.x;
    if (i >= n4) return;
    float4 v = ((const float4*)src)[i];
    uint2 p;
    p.x = (uint)f2bf(v.x) | ((uint)f2bf(v.y) << 16);
    p.y = (uint)f2bf(v.z) | ((uint)f2bf(v.w) << 16);
    ((uint2*)dst)[i] = p;
}

// W[K][256] fp32 -> Wt[256][K] bf16
__global__ void wtrans_kernel(const float* __restrict__ W, ushort* __restrict__ Wt, int K) {
    int tid = blockIdx.x * blockDim.x + threadIdx.x;
    if (tid >= 256 * K) return;
    int k = tid >> 8, n = tid & 255;
    Wt[n * K + k] = f2bf(W[k * 256 + n]);
}

// ---------------- MFMA GEMM: Y[M][256] = A[M][K] * W[K][256], all bf16 ----------------
template<int K>
__global__ __launch_bounds__(256) void mfma_gemm(
        const ushort* __restrict__ A,    // [M][K] bf16
        const ushort* __restrict__ Wt,   // [256][K] bf16 (transposed)
        ushort* __restrict__ Y) {        // [M][256] bf16
    constexpr int KP = K + 8;
    constexpr int K8 = K / 8;
    __shared__ ushort As[16 * KP];
    const int m0 = blockIdx.x * 16;
    const int t = threadIdx.x;
    const uint4* Ag = (const uint4*)(A + (size_t)m0 * K);
    uint4* As4 = (uint4*)As;
    for (int i = t; i < 16 * K8; i += 256) {
        int r = i / K8, c8 = i % K8;
        As4[r * (K8 + 1) + c8] = Ag[i];
    }
    __syncthreads();
    const int wv = t >> 6, lane = t & 63;
    const int n0 = wv * 64;
    const int mrow = lane & 15, q = lane >> 4;
    f32x4 acc[4];
#pragma unroll
    for (int i = 0; i < 4; i++) acc[i] = (f32x4){0.f, 0.f, 0.f, 0.f};
    const ushort* arow = As + mrow * KP + q * 8;
#pragma unroll
    for (int k0 = 0; k0 < K; k0 += 32) {
        bf16x8 a = *(const bf16x8*)(arow + k0);
#pragma unroll
        for (int i = 0; i < 4; i++) {
            bf16x8 b = *(const bf16x8*)(Wt + (size_t)(n0 + i * 16 + mrow) * K + k0 + q * 8);
            acc[i] = __builtin_amdgcn_mfma_f32_16x16x32_bf16(a, b, acc[i], 0, 0, 0);
        }
    }
#pragma unroll
    for (int i = 0; i < 4; i++)
#pragma unroll
        for (int r = 0; r < 4; r++)
            Y[(size_t)(m0 + q * 4 + r) * 256 + n0 + i * 16 + mrow] = f2bf(acc[i][r]);
}

// ---------------- attention logits ----------------

template<int H>
__global__ __launch_bounds__(256) void al_wave_kernel(
        const uint* __restrict__ xwb,                    // row stride 128 uints
        const float* __restrict__ a_src, const float* __restrict__ a_dst,
        float* __restrict__ als, float* __restrict__ ald) {
    int wid = (blockIdx.x * 256 + threadIdx.x) >> 6;
    int lane = threadIdx.x & 63;
    if (wid >= N_NODES) return;
    uint2 u = ((const uint2*)(xwb + (size_t)wid * 128))[lane];
    int col = lane * 4;
    float x0 = bfl(u.x), x1 = bfh(u.x), x2 = bfl(u.y), x3 = bfh(u.y);
    float s = x0 * a_src[col] + x1 * a_src[col + 1] + x2 * a_src[col + 2] + x3 * a_src[col + 3];
    float d = x0 * a_dst[col] + x1 * a_dst[col + 1] + x2 * a_dst[col + 2] + x3 * a_dst[col + 3];
#pragma unroll
    for (int o = 32 / H; o > 0; o >>= 1) {
        s += __shfl_xor(s, o, 64);
        d += __shfl_xor(d, o, 64);
    }
    if ((lane & (64 / H - 1)) == 0) {
        int h = lane / (64 / H);
        als[wid * H + h] = s;
        ald[wid * H + h] = d;
    }
}

#define UN 8

// layer-1 gather: wave per node, 8-deep batched edge loads, ELU, bf16-packed out
__global__ __launch_bounds__(256) void gat_gather1(
        const int* __restrict__ row_start, const int* __restrict__ srclist,
        const float* __restrict__ als, const float* __restrict__ ald,
        const uint* __restrict__ xwb,                    // row stride 128 uints
        const float* __restrict__ bias,
        ushort* __restrict__ emb1b) {                    // [N][256] bf16
    const int wid = blockIdx.x * 4 + (threadIdx.x >> 6);
    const int lane = threadIdx.x & 63;
    const int h = lane >> 3;
    const float ald_n = ald[wid * HEADS_1 + h];
    const int beg = row_start[wid], end = row_start[wid + 1];
    const uint2* rowp = (const uint2*)xwb;

    float ex0 = __expf(leaky(als[wid * HEADS_1 + h] + ald_n));
    uint2 u = rowp[(size_t)wid * 64 + lane];
    float den = ex0;
    float a0 = ex0 * bfl(u.x), a1 = ex0 * bfh(u.x);
    float a2 = ex0 * bfl(u.y), a3 = ex0 * bfh(u.y);

    for (int i = beg; i < end; i += UN) {
        int ss[UN]; uint2 rr[UN]; float ee[UN];
#pragma unroll
        for (int j = 0; j < UN; j++) ss[j] = srclist[min(i + j, end - 1)];
#pragma unroll
        for (int j = 0; j < UN; j++) rr[j] = rowp[(size_t)ss[j] * 64 + lane];
#pragma unroll
        for (int j = 0; j < UN; j++) ee[j] = als[ss[j] * HEADS_1 + h];
#pragma unroll
        for (int j = 0; j < UN; j++) {
            float ex = (i + j < end) ? __expf(leaky(ee[j] + ald_n)) : 0.f;
            den += ex;
            a0 += ex * bfl(rr[j].x); a1 += ex * bfh(rr[j].x);
            a2 += ex * bfl(rr[j].y); a3 += ex * bfh(rr[j].y);
        }
    }
    float inv = 1.f / den;
    float4 bv = ((const float4*)bias)[lane];
    float4 r;
    r.x = a0 * inv + bv.x; r.y = a1 * inv + bv.y;
    r.z = a2 * inv + bv.z; r.w = a3 * inv + bv.w;
    r.x = r.x > 0.f ? r.x : __expf(r.x) - 1.f;
    r.y = r.y > 0.f ? r.y : __expf(r.y) - 1.f;
    r.z = r.z > 0.f ? r.z : __expf(r.z) - 1.f;
    r.w = r.w > 0.f ? r.w : __expf(r.w) - 1.f;
    uint2 p;
    p.x = (uint)f2bf(r.x) | ((uint)f2bf(r.y) << 16);
    p.y = (uint)f2bf(r.z) | ((uint)f2bf(r.w) << 16);
    ((uint2*)emb1b)[(size_t)wid * 64 + lane] = p;
}

// layer-2 gather fused with normalize+pack: emb2 never materialized
__global__ __launch_bounds__(256) void gat_gather2(
        const int* __restrict__ row_start, const int* __restrict__ srclist,
        const float* __restrict__ als, const float* __restrict__ ald,
        const uint* __restrict__ xwb,                    // row stride 128 uints
        const float* __restrict__ bias,
        const ushort* __restrict__ emb1b,                // [N][256] bf16
        uint* __restrict__ embn) {                       // row stride 256 uints
    const int wid = blockIdx.x * 4 + (threadIdx.x >> 6);
    const int lane = threadIdx.x & 63;
    const float ald_n = ald[wid];
    const int beg = row_start[wid], end = row_start[wid + 1];
    const uint2* rowp = (const uint2*)xwb;

    float ex0 = __expf(leaky(als[wid] + ald_n));
    uint2 u = rowp[(size_t)wid * 64 + lane];
    float den = ex0;
    float a0 = ex0 * bfl(u.x), a1 = ex0 * bfh(u.x);
    float a2 = ex0 * bfl(u.y), a3 = ex0 * bfh(u.y);

    for (int i = beg; i < end; i += UN) {
        int ss[UN]; uint2 rr[UN]; float ee[UN];
#pragma unroll
        for (int j = 0; j < UN; j++) ss[j] = srclist[min(i + j, end - 1)];
#pragma unroll
        for (int j = 0; j < UN; j++) rr[j] = rowp[(size_t)ss[j] * 64 + lane];
#pragma unroll
        for (int j = 0; j < UN; j++) ee[j] = als[ss[j]];
#pragma unroll
        for (int j = 0; j < UN; j++) {
            float ex = (i + j < end) ? __expf(leaky(ee[j] + ald_n)) : 0.f;
            den += ex;
            a0 += ex * bfl(rr[j].x); a1 += ex * bfh(rr[j].x);
            a2 += ex * bfl(rr[j].y); a3 += ex * bfh(rr[j].y);
        }
    }
    float inv = 1.f / den;
    float4 bv = ((const float4*)bias)[lane];
    float4 e2;
    e2.x = a0 * inv + bv.x; e2.y = a1 * inv + bv.y;
    e2.z = a2 * inv + bv.z; e2.w = a3 * inv + bv.w;
    uint2 u1 = ((const uint2*)emb1b)[(size_t)wid * 64 + lane];
    float4 e1;
    e1.x = bfl(u1.x); e1.y = bfh(u1.x); e1.z = bfl(u1.y); e1.w = bfh(u1.y);

    float ssum = e1.x * e1.x + e1.y * e1.y + e1.z * e1.z + e1.w * e1.w
               + e2.x * e2.x + e2.y * e2.y + e2.z * e2.z + e2.w * e2.w;
#pragma unroll
    for (int o = 32; o > 0; o >>= 1) ssum += __shfl_xor(ssum, o, 64);
    float innv = 1.f / fmaxf(sqrtf(ssum), 1e-8f);

    uint2 p1, p2;
    p1.x = (uint)f2bf(e1.x * innv) | ((uint)f2bf(e1.y * innv) << 16);
    p1.y = (uint)f2bf(e1.z * innv) | ((uint)f2bf(e1.w * innv) << 16);
    p2.x = (uint)f2bf(e2.x * innv) | ((uint)f2bf(e2.y * innv) << 16);
    p2.y = (uint)f2bf(e2.z * innv) | ((uint)f2bf(e2.w * innv) << 16);
    ((uint2*)embn)[(size_t)wid * 128 + lane] = p1;
    ((uint2*)embn)[(size_t)wid * 128 + 64 + lane] = p2;
}

// ---------------- MFMA contrastive loss ----------------

#define ANCH 16                         // anchors per block (walk segment)
#define MAXROWS (ANCH + 2 * WINDOW)     // 26 LDS rows max
#define ROWP 520                        // 512 + 8 ushort pad (16B): conflict-free A/B frags

// one block per 16-anchor segment; sims via mfma_f32_16x16x32_bf16.
// 12 tile-jobs of 16 candidates: jobs 0..9 = neg cands (B-frags from global),
// jobs 10..11 = pos rows (B-frags from LDS walk rows).
__global__ __launch_bounds__(256) void loss_mfma_kernel(
        const uint* __restrict__ embn,     // [N][512] bf16 (2-packed uints)
        const int* __restrict__ walks, const int* __restrict__ negs,
        float* __restrict__ out) {
    __shared__ __align__(16) ushort srows[MAXROWS][ROWP];
    __shared__ int wids[MAXROWS];
    __shared__ int snid[160];
    __shared__ float possum[16];
    __shared__ float negsum[16];
    const int blk = blockIdx.x;
    const int b = blk >> 2;                  // walk
    const int l0 = (blk & 3) * ANCH;         // first anchor of segment
    const int base = (l0 - WINDOW) > 0 ? (l0 - WINDOW) : 0;
    const int hi = (l0 + ANCH - 1 + WINDOW) < (WALK_LEN - 1) ? (l0 + ANCH - 1 + WINDOW) : (WALK_LEN - 1);
    const int cnt = hi - base + 1;           // 21..26
    const int t = threadIdx.x;
    const int w = t >> 6, lane = t & 63;
    if (t < cnt) wids[t] = walks[b * WALK_LEN + base + t];
    if (t >= 64 && t < 64 + 160) snid[t - 64] = negs[(b * WALK_LEN + l0) * NEG_S + (t - 64)];
    if (t >= 224 && t < 240) { possum[t - 224] = 0.f; negsum[t - 224] = 0.f; }
    __syncthreads();
    const uint4* g4 = (const uint4*)embn;    // row stride 64 uint4
    for (int r = w; r < cnt; r += 4)
        *((uint4*)&srows[r][0] + lane) = g4[(size_t)wids[r] * 64 + lane];
    __syncthreads();

    const int mrow = lane & 15, q = lane >> 4;
    const int arow = (l0 - base) + mrow;     // wrow of anchor #mrow
    const ushort* embs = (const ushort*)embn;
    const ushort* ap = &srows[arow][q * 8];

    for (int job = w; job < 12; job += 4) {
        f32x4 acc0 = {0.f, 0.f, 0.f, 0.f};
        f32x4 acc1 = {0.f, 0.f, 0.f, 0.f};
        if (job < 10) {
            // ---- neg tile: cands c = 16*job .. +15, col = mrow ----
            const int c = job * 16 + mrow;
            const int node = snid[c];
            const ushort* bp = embs + (size_t)node * 512 + q * 8;
#pragma unroll
            for (int k0 = 0; k0 < 256; k0 += 32) {
                bf16x8 a0 = *(const bf16x8*)(ap + k0);
                bf16x8 b0 = *(const bf16x8*)(bp + k0);
                acc0 = __builtin_amdgcn_mfma_f32_16x16x32_bf16(a0, b0, acc0, 0, 0, 0);
                bf16x8 a1 = *(const bf16x8*)(ap + k0 + 256);
                bf16x8 b1 = *(const bf16x8*)(bp + k0 + 256);
                acc1 = __builtin_amdgcn_mfma_f32_16x16x32_bf16(a1, b1, acc1, 0, 0, 0);
            }
            const int owner = c / 10;
#pragma unroll
            for (int reg = 0; reg < 4; reg++) {
                const int a_local = q * 4 + reg;
                float e = 0.f;
                if (owner == a_local) {
                    const int l_a = l0 + a_local;
                    bool msk = false;
#pragma unroll
                    for (int dj = -WINDOW; dj <= WINDOW; dj++) {
                        if (dj == 0) continue;
                        int p = l_a + dj;
                        if (p >= 0 && p < WALK_LEN && wids[p - base] == node) msk = true;
                    }
                    if (!msk) e = __expf((acc0[reg] + acc1[reg]) * INV_TEMP);
                }
#pragma unroll
                for (int o = 1; o < 16; o <<= 1) e += __shfl_xor(e, o, 64);
                if (mrow == 0 && e != 0.f) atomicAdd(&negsum[a_local], e);
            }
        } else {
            // ---- pos tile: wrows r = 16*(job-10) .. +15 ----
            const int r = (job - 10) * 16 + mrow;
            const int rc = r < (cnt - 1) ? r : (cnt - 1);
            const ushort* bp = &srows[rc][q * 8];
#pragma unroll
            for (int k0 = 0; k0 < 256; k0 += 32) {
                bf16x8 a0 = *(const bf16x8*)(ap + k0);
                bf16x8 b0 = *(const bf16x8*)(bp + k0);
                acc0 = __builtin_amdgcn_mfma_f32_16x16x32_bf16(a0, b0, acc0, 0, 0, 0);
                bf16x8 a1 = *(const bf16x8*)(ap + k0 + 256);
                bf16x8 b1 = *(const bf16x8*)(bp + k0 + 256);
                acc1 = __builtin_amdgcn_mfma_f32_16x16x32_bf16(a1, b1, acc1, 0, 0, 0);
            }
            const int pg = base + r;                 // walk position of this wrow
#pragma unroll
            for (int reg = 0; reg < 4; reg++) {
                const int a_local = q * 4 + reg;
                const int l_a = l0 + a_local;
                const int d = pg - l_a;
                bool use = (r < cnt) && (d != 0) && (d >= -WINDOW) && (d <= WINDOW);
                float e = use ? __expf((acc0[reg] + acc1[reg]) * INV_TEMP) : 0.f;
#pragma unroll
                for (int o = 1; o < 16; o <<= 1) e += __shfl_xor(e, o, 64);
                if (mrow == 0 && e != 0.f) atomicAdd(&possum[a_local], e);
            }
        }
    }
    __syncthreads();
    if (t < 16) {
        float term = logf(1.f + negsum[t] / possum[t]);   // possum > 0 always
#pragma unroll
        for (int o = 8; o > 0; o >>= 1) term += __shfl_xor(term, o, 64);
        if (t == 0) atomicAdd(out, term);
    }
}

extern "C" void kernel_launch(void* const* d_in, const int* in_sizes, int n_in,
                              void* d_out, int out_size, void* d_ws, size_t ws_size,
                              hipStream_t stream) {
    const float* x      = (const float*)d_in[0];
    const int*   ei     = (const int*)d_in[1];
    const int*   walks  = (const int*)d_in[2];
    const int*   negs   = (const int*)d_in[3];
    const float* W1     = (const float*)d_in[4];
    const float* a_src1 = (const float*)d_in[5];
    const float* a_dst1 = (const float*)d_in[6];
    const float* b1     = (const float*)d_in[7];
    const float* W2     = (const float*)d_in[8];
    const float* a_src2 = (const float*)d_in[9];
    const float* a_dst2 = (const float*)d_in[10];
    const float* b2     = (const float*)d_in[11];
    float* out = (float*)d_out;

    float* ws = (float*)d_ws;
    size_t off = 0;
    float* r_xwb   = ws + off; off += (size_t)N_NODES * 128;   // [N][256] bf16
    float* r_emb1b = ws + off; off += (size_t)N_NODES * 128;   // [N][256] bf16
    float* r_embn  = ws + off; off += (size_t)N_NODES * 256;   // [N][512] bf16 (2-packed)
    float* r_xb    = ws + off; off += (size_t)N_NODES * 64;    // [N][128] bf16
    float* r_wt1   = ws + off; off += 256 * 64;                // [256][128] bf16
    float* r_wt2   = ws + off; off += 256 * 128;               // [256][256] bf16
    float* als1  = ws + off; off += N_NODES * HEADS_1;
    float* ald1  = ws + off; off += N_NODES * HEADS_1;
    float* als2  = ws + off; off += N_NODES;
    float* ald2  = ws + off; off += N_NODES;
    int* deg       = (int*)(ws + off); off += N_NODES;
    int* excl      = (int*)(ws + off); off += N_NODES;
    int* bsum      = (int*)(ws + off); off += 256;
    int* row_start = (int*)(ws + off); off += N_NODES + 1;
    int* cursor    = (int*)(ws + off); off += N_NODES;
    int* srclist   = (int*)(ws + off); off += E_EDGES;
    ushort* xwb   = (ushort*)r_xwb;
    ushort* emb1b = (ushort*)r_emb1b;
    uint*   embn  = (uint*)r_embn;
    ushort* xb    = (ushort*)r_xb;
    ushort* wt1   = (ushort*)r_wt1;
    ushort* wt2   = (ushort*)r_wt2;

    hipMemsetAsync(out, 0, sizeof(float) * out_size, stream);
    hipMemsetAsync(deg, 0, sizeof(int) * N_NODES, stream);
    hipMemsetAsync(cursor, 0, sizeof(int) * N_NODES, stream);

    // ---- CSR build (shared by both layers) ----
    deg_kernel<<<(E_EDGES + 255) / 256, 256, 0, stream>>>(ei, deg);
    scan_a<<<SCAN_BLOCKS, 256, 0, stream>>>(deg, excl, bsum);
    scan_b<<<1, 256, 0, stream>>>(bsum);
    scan_c2<<<SCAN_BLOCKS, 256, 0, stream>>>(excl, bsum, row_start);
    bucket_kernel<<<(E_EDGES + 255) / 256, 256, 0, stream>>>(ei, row_start, cursor, srclist);

    // ---- bf16 conversions ----
    f32_to_bf16_kernel<<<(N_NODES * FDIM_IN / 4 + 255) / 256, 256, 0, stream>>>(
        x, (uint*)xb, N_NODES * FDIM_IN / 4);
    wtrans_kernel<<<(256 * 128 + 255) / 256, 256, 0, stream>>>(W1, wt1, 128);
    wtrans_kernel<<<(256 * 256 + 255) / 256, 256, 0, stream>>>(W2, wt2, 256);

    // ---- layer 1 (heads=8, hid=32) ----
    mfma_gemm<128><<<N_NODES / 16, 256, 0, stream>>>(xb, wt1, xwb);
    al_wave_kernel<HEADS_1><<<(N_NODES * 64 + 255) / 256, 256, 0, stream>>>(
        (const uint*)xwb, a_src1, a_dst1, als1, ald1);
    gat_gather1<<<N_NODES / 4, 256, 0, stream>>>(
        row_start, srclist, als1, ald1, (const uint*)xwb, b1, emb1b);

    // ---- layer 2 (heads=1, hid=256), fused normalize+pack ----
    mfma_gemm<256><<<N_NODES / 16, 256, 0, stream>>>(emb1b, wt2, xwb);
    al_wave_kernel<1><<<(N_NODES * 64 + 255) / 256, 256, 0, stream>>>(
        (const uint*)xwb, a_src2, a_dst2, als2, ald2);
    gat_gather2<<<N_NODES / 4, 256, 0, stream>>>(
        row_start, srclist, als2, ald2, (const uint*)xwb, b2, emb1b, embn);

    // ---- contrastive loss (MFMA) ----
    loss_mfma_kernel<<<NUM_WALKS * 4, 256, 0, stream>>>(embn, walks, negs, out);
}

// Round 9
// 438.549 us; speedup vs baseline: 6.6348x; 1.1339x over previous
//
#include <hip/hip_runtime.h>
#include <math.h>

#define N_NODES 50000
#define E_EDGES 800000
#define FDIM_IN 128
#define HID_1 32
#define HEADS_1 8
#define H1DIM 256
#define NUM_WALKS 512
#define WALK_LEN 64
#define WINDOW 5
#define NEG_S 10
#define TEMP 0.07f
#define INV_TEMP (1.0f / 0.07f)
#define NEG_SLOPE 0.2f

#define SCAN_BLOCKS ((N_NODES + 255) / 256)   // 196

typedef unsigned int uint;
typedef unsigned short ushort;
typedef long long i64_t;
typedef __attribute__((ext_vector_type(8))) short bf16x8;
typedef __attribute__((ext_vector_type(4))) float f32x4;
typedef __attribute__((ext_vector_type(2))) float vf2;

__device__ __forceinline__ float leaky(float v) {
    return v > 0.f ? v : v * NEG_SLOPE;
}

__device__ __forceinline__ float bfl(uint u) { return __uint_as_float(u << 16); }
__device__ __forceinline__ float bfh(uint u) { return __uint_as_float(u & 0xffff0000u); }

__device__ __forceinline__ ushort f2bf(float x) {
    uint u = __float_as_uint(x);
    u = u + 0x7fffu + ((u >> 16) & 1u);   // round-to-nearest-even
    return (ushort)(u >> 16);
}

// pack 4 f32 -> 4 fp8(e4m3) in one uint (HW converter; self-consistent with decode)
__device__ __forceinline__ uint pk4fp8(float a, float b, float c, float d) {
    int u = __builtin_amdgcn_cvt_pk_fp8_f32(a, b, 0, false);
    u = __builtin_amdgcn_cvt_pk_fp8_f32(c, d, u, true);
    return (uint)u;
}

// ---------------- CSR build ----------------

__global__ void deg_kernel(const int* __restrict__ ei, int* __restrict__ deg) {
    int e = blockIdx.x * blockDim.x + threadIdx.x;
    if (e < E_EDGES) atomicAdd(&deg[ei[E_EDGES + e]], 1);
}

__global__ __launch_bounds__(256) void scan_a(const int* __restrict__ deg,
                                              int* __restrict__ excl,
                                              int* __restrict__ bsum) {
    __shared__ int s[256];
    int t = threadIdx.x;
    int i = blockIdx.x * 256 + t;
    int v = (i < N_NODES) ? deg[i] : 0;
    s[t] = v;
    __syncthreads();
    for (int off = 1; off < 256; off <<= 1) {
        int tmp = (t >= off) ? s[t - off] : 0;
        __syncthreads();
        s[t] += tmp;
        __syncthreads();
    }
    if (i < N_NODES) excl[i] = s[t] - v;
    if (t == 255) bsum[blockIdx.x] = s[255];
}

__global__ __launch_bounds__(256) void scan_b(int* __restrict__ bsum) {
    __shared__ int s[256];
    int t = threadIdx.x;
    int v = (t < SCAN_BLOCKS) ? bsum[t] : 0;
    s[t] = v;
    __syncthreads();
    for (int off = 1; off < 256; off <<= 1) {
        int tmp = (t >= off) ? s[t - off] : 0;
        __syncthreads();
        s[t] += tmp;
        __syncthreads();
    }
    if (t < SCAN_BLOCKS) bsum[t] = s[t] - v;   // exclusive
}

__global__ void scan_c2(int* __restrict__ excl, const int* __restrict__ bsum,
                        int* __restrict__ row_start) {
    int i = blockIdx.x * blockDim.x + threadIdx.x;
    if (i < N_NODES) row_start[i] = excl[i] + bsum[i >> 8];
    if (i == 0) row_start[N_NODES] = E_EDGES;
}

__global__ void bucket_kernel(const int* __restrict__ ei,
                              const int* __restrict__ row_start,
                              int* __restrict__ cursor,
                              int* __restrict__ srclist) {
    int e = blockIdx.x * blockDim.x + threadIdx.x;
    if (e >= E_EDGES) return;
    int dst = ei[E_EDGES + e];
    int pos = atomicAdd(&cursor[dst], 1);
    srclist[row_start[dst] + pos] = ei[e];
}

// ---------------- dtype conversion ----------------

__global__ void f32_to_bf16_kernel(const float* __restrict__ src, uint* __restrict__ dst, int n4) {
    int i = blockIdx.x * blockDim.x + threadIdx.x;
    if (i >= n4) return;
    float4 v = ((const float4*)src)[i];
    uint2 p;
    p.x = (uint)f2bf(v.x) | ((uint)f2bf(v.y) << 16);
    p.y = (uint)f2bf(v.z) | ((uint)f2bf(v.w) << 16);
    ((uint2*)dst)[i] = p;
}

// W[K][256] fp32 -> Wt[256][K] bf16
__global__ void wtrans_kernel(const float* __restrict__ W, ushort* __restrict__ Wt, int K) {
    int tid = blockIdx.x * blockDim.x + threadIdx.x;
    if (tid >= 256 * K) return;
    int k = tid >> 8, n = tid & 255;
    Wt[n * K + k] = f2bf(W[k * 256 + n]);
}

// ---------------- MFMA GEMM: Y8[M][256] (fp8) = A[M][K] * W[K][256], bf16 in ----------------
template<int K>
__global__ __launch_bounds__(256) void mfma_gemm(
        const ushort* __restrict__ A,    // [M][K] bf16
        const ushort* __restrict__ Wt,   // [256][K] bf16 (transposed)
        uint* __restrict__ Y8) {         // [M][256] fp8, 64 uints/row
    constexpr int KP = K + 8;
    constexpr int K8 = K / 8;
    __shared__ ushort As[16 * KP];
    __shared__ float Cs[16][260];
    const int m0 = blockIdx.x * 16;
    const int t = threadIdx.x;
    const uint4* Ag = (const uint4*)(A + (size_t)m0 * K);
    uint4* As4 = (uint4*)As;
    for (int i = t; i < 16 * K8; i += 256) {
        int r = i / K8, c8 = i % K8;
        As4[r * (K8 + 1) + c8] = Ag[i];
    }
    __syncthreads();
    const int wv = t >> 6, lane = t & 63;
    const int n0 = wv * 64;
    const int mrow = lane & 15, q = lane >> 4;
    f32x4 acc[4];
#pragma unroll
    for (int i = 0; i < 4; i++) acc[i] = (f32x4){0.f, 0.f, 0.f, 0.f};
    const ushort* arow = As + mrow * KP + q * 8;
#pragma unroll
    for (int k0 = 0; k0 < K; k0 += 32) {
        bf16x8 a = *(const bf16x8*)(arow + k0);
#pragma unroll
        for (int i = 0; i < 4; i++) {
            bf16x8 b = *(const bf16x8*)(Wt + (size_t)(n0 + i * 16 + mrow) * K + k0 + q * 8);
            acc[i] = __builtin_amdgcn_mfma_f32_16x16x32_bf16(a, b, acc[i], 0, 0, 0);
        }
    }
#pragma unroll
    for (int i = 0; i < 4; i++)
#pragma unroll
        for (int r = 0; r < 4; r++)
            Cs[q * 4 + r][n0 + i * 16 + mrow] = acc[i][r];
    __syncthreads();
    // thread t packs row t>>4, cols (t&15)*16 .. +15 into one uint4
    const int row = t >> 4, c0 = (t & 15) * 16;
    const float* cp = &Cs[row][c0];
    uint4 o;
    o.x = pk4fp8(cp[0],  cp[1],  cp[2],  cp[3]);
    o.y = pk4fp8(cp[4],  cp[5],  cp[6],  cp[7]);
    o.z = pk4fp8(cp[8],  cp[9],  cp[10], cp[11]);
    o.w = pk4fp8(cp[12], cp[13], cp[14], cp[15]);
    ((uint4*)(Y8 + (size_t)(m0 + row) * 64))[t & 15] = o;
}

// ---------------- attention logits ----------------

template<int H>
__global__ __launch_bounds__(256) void al_wave_kernel(
        const uint* __restrict__ xw8,                    // fp8 rows, 64 uints/row
        const float* __restrict__ a_src, const float* __restrict__ a_dst,
        float* __restrict__ als, float* __restrict__ ald) {
    int wid = (blockIdx.x * 256 + threadIdx.x) >> 6;
    int lane = threadIdx.x & 63;
    if (wid >= N_NODES) return;
    uint u = xw8[(size_t)wid * 64 + lane];
    vf2 lo = __builtin_amdgcn_cvt_pk_f32_fp8((int)u, false);
    vf2 hi = __builtin_amdgcn_cvt_pk_f32_fp8((int)u, true);
    int col = lane * 4;
    float s = lo[0] * a_src[col] + lo[1] * a_src[col + 1] + hi[0] * a_src[col + 2] + hi[1] * a_src[col + 3];
    float d = lo[0] * a_dst[col] + lo[1] * a_dst[col + 1] + hi[0] * a_dst[col + 2] + hi[1] * a_dst[col + 3];
#pragma unroll
    for (int o = 32 / H; o > 0; o >>= 1) {
        s += __shfl_xor(s, o, 64);
        d += __shfl_xor(d, o, 64);
    }
    if ((lane & (64 / H - 1)) == 0) {
        int h = lane / (64 / H);
        als[wid * H + h] = s;
        ald[wid * H + h] = d;
    }
}

#define UN 8

// layer-1 gather: wave per node, 8-deep batched edge loads (fp8 rows), ELU, bf16 out
__global__ __launch_bounds__(256) void gat_gather1(
        const int* __restrict__ row_start, const int* __restrict__ srclist,
        const float* __restrict__ als, const float* __restrict__ ald,
        const uint* __restrict__ xw8,                    // fp8 rows, 64 uints/row
        const float* __restrict__ bias,
        ushort* __restrict__ emb1b) {                    // [N][256] bf16
    const int wid = blockIdx.x * 4 + (threadIdx.x >> 6);
    const int lane = threadIdx.x & 63;
    const int h = lane >> 3;
    const float ald_n = ald[wid * HEADS_1 + h];
    const int beg = row_start[wid], end = row_start[wid + 1];

    float ex0 = __expf(leaky(als[wid * HEADS_1 + h] + ald_n));
    uint u = xw8[(size_t)wid * 64 + lane];
    vf2 lo = __builtin_amdgcn_cvt_pk_f32_fp8((int)u, false);
    vf2 hi = __builtin_amdgcn_cvt_pk_f32_fp8((int)u, true);
    float den = ex0;
    float a0 = ex0 * lo[0], a1 = ex0 * lo[1];
    float a2 = ex0 * hi[0], a3 = ex0 * hi[1];

    for (int i = beg; i < end; i += UN) {
        int ss[UN]; uint rr[UN]; float ee[UN];
#pragma unroll
        for (int j = 0; j < UN; j++) ss[j] = srclist[min(i + j, end - 1)];
#pragma unroll
        for (int j = 0; j < UN; j++) rr[j] = xw8[(size_t)ss[j] * 64 + lane];
#pragma unroll
        for (int j = 0; j < UN; j++) ee[j] = als[ss[j] * HEADS_1 + h];
#pragma unroll
        for (int j = 0; j < UN; j++) {
            float ex = (i + j < end) ? __expf(leaky(ee[j] + ald_n)) : 0.f;
            vf2 l2 = __builtin_amdgcn_cvt_pk_f32_fp8((int)rr[j], false);
            vf2 h2 = __builtin_amdgcn_cvt_pk_f32_fp8((int)rr[j], true);
            den += ex;
            a0 += ex * l2[0]; a1 += ex * l2[1];
            a2 += ex * h2[0]; a3 += ex * h2[1];
        }
    }
    float inv = 1.f / den;
    float4 bv = ((const float4*)bias)[lane];
    float4 r;
    r.x = a0 * inv + bv.x; r.y = a1 * inv + bv.y;
    r.z = a2 * inv + bv.z; r.w = a3 * inv + bv.w;
    r.x = r.x > 0.f ? r.x : __expf(r.x) - 1.f;
    r.y = r.y > 0.f ? r.y : __expf(r.y) - 1.f;
    r.z = r.z > 0.f ? r.z : __expf(r.z) - 1.f;
    r.w = r.w > 0.f ? r.w : __expf(r.w) - 1.f;
    uint2 p;
    p.x = (uint)f2bf(r.x) | ((uint)f2bf(r.y) << 16);
    p.y = (uint)f2bf(r.z) | ((uint)f2bf(r.w) << 16);
    ((uint2*)emb1b)[(size_t)wid * 64 + lane] = p;
}

// layer-2 gather fused with normalize + fp8 pack of embn
__global__ __launch_bounds__(256) void gat_gather2(
        const int* __restrict__ row_start, const int* __restrict__ srclist,
        const float* __restrict__ als, const float* __restrict__ ald,
        const uint* __restrict__ xw8,                    // fp8 rows, 64 uints/row
        const float* __restrict__ bias,
        const ushort* __restrict__ emb1b,                // [N][256] bf16
        uint* __restrict__ embn8) {                      // [N][512] fp8, 128 uints/row
    const int wid = blockIdx.x * 4 + (threadIdx.x >> 6);
    const int lane = threadIdx.x & 63;
    const float ald_n = ald[wid];
    const int beg = row_start[wid], end = row_start[wid + 1];

    float ex0 = __expf(leaky(als[wid] + ald_n));
    uint u = xw8[(size_t)wid * 64 + lane];
    vf2 lo = __builtin_amdgcn_cvt_pk_f32_fp8((int)u, false);
    vf2 hi = __builtin_amdgcn_cvt_pk_f32_fp8((int)u, true);
    float den = ex0;
    float a0 = ex0 * lo[0], a1 = ex0 * lo[1];
    float a2 = ex0 * hi[0], a3 = ex0 * hi[1];

    for (int i = beg; i < end; i += UN) {
        int ss[UN]; uint rr[UN]; float ee[UN];
#pragma unroll
        for (int j = 0; j < UN; j++) ss[j] = srclist[min(i + j, end - 1)];
#pragma unroll
        for (int j = 0; j < UN; j++) rr[j] = xw8[(size_t)ss[j] * 64 + lane];
#pragma unroll
        for (int j = 0; j < UN; j++) ee[j] = als[ss[j]];
#pragma unroll
        for (int j = 0; j < UN; j++) {
            float ex = (i + j < end) ? __expf(leaky(ee[j] + ald_n)) : 0.f;
            vf2 l2 = __builtin_amdgcn_cvt_pk_f32_fp8((int)rr[j], false);
            vf2 h2 = __builtin_amdgcn_cvt_pk_f32_fp8((int)rr[j], true);
            den += ex;
            a0 += ex * l2[0]; a1 += ex * l2[1];
            a2 += ex * h2[0]; a3 += ex * h2[1];
        }
    }
    float inv = 1.f / den;
    float4 bv = ((const float4*)bias)[lane];
    float4 e2;
    e2.x = a0 * inv + bv.x; e2.y = a1 * inv + bv.y;
    e2.z = a2 * inv + bv.z; e2.w = a3 * inv + bv.w;
    uint2 u1 = ((const uint2*)emb1b)[(size_t)wid * 64 + lane];
    float4 e1;
    e1.x = bfl(u1.x); e1.y = bfh(u1.x); e1.z = bfl(u1.y); e1.w = bfh(u1.y);

    float ssum = e1.x * e1.x + e1.y * e1.y + e1.z * e1.z + e1.w * e1.w
               + e2.x * e2.x + e2.y * e2.y + e2.z * e2.z + e2.w * e2.w;
#pragma unroll
    for (int o = 32; o > 0; o >>= 1) ssum += __shfl_xor(ssum, o, 64);
    float innv = 1.f / fmaxf(sqrtf(ssum), 1e-8f);

    uint p1 = pk4fp8(e1.x * innv, e1.y * innv, e1.z * innv, e1.w * innv);
    uint p2 = pk4fp8(e2.x * innv, e2.y * innv, e2.z * innv, e2.w * innv);
    embn8[(size_t)wid * 128 + lane] = p1;        // dims 0..255   (emb1 part)
    embn8[(size_t)wid * 128 + 64 + lane] = p2;   // dims 256..511 (emb2 part)
}

// ---------------- MFMA contrastive loss (fp8) ----------------

#define ANCH 16                         // anchors per block (walk segment)
#define MAXROWS (ANCH + 2 * WINDOW)     // 26 LDS rows max
#define ROWU 132                        // 512 B row + 16 B pad, in uints

// one block per 16-anchor segment; sims via mfma_f32_16x16x32_fp8_fp8.
// 12 tile-jobs of 16 candidates: jobs 0..9 = neg cands (B-frags from global),
// jobs 10..11 = pos rows (B-frags from LDS walk rows).
__global__ __launch_bounds__(256) void loss_mfma_kernel(
        const uint* __restrict__ embn8,    // [N][512] fp8, 128 uints/row
        const int* __restrict__ walks, const int* __restrict__ negs,
        float* __restrict__ out) {
    __shared__ __align__(16) uint srows8[MAXROWS * ROWU];   // 13.7 KB
    __shared__ int wids[MAXROWS];
    __shared__ int snid[160];
    __shared__ float possum[16];
    __shared__ float negsum[16];
    const int blk = blockIdx.x;
    const int b = blk >> 2;                  // walk
    const int l0 = (blk & 3) * ANCH;         // first anchor of segment
    const int base = (l0 - WINDOW) > 0 ? (l0 - WINDOW) : 0;
    const int hi = (l0 + ANCH - 1 + WINDOW) < (WALK_LEN - 1) ? (l0 + ANCH - 1 + WINDOW) : (WALK_LEN - 1);
    const int cnt = hi - base + 1;           // 21..26
    const int t = threadIdx.x;
    const int w = t >> 6, lane = t & 63;
    if (t < cnt) wids[t] = walks[b * WALK_LEN + base + t];
    if (t >= 64 && t < 64 + 160) snid[t - 64] = negs[(b * WALK_LEN + l0) * NEG_S + (t - 64)];
    if (t >= 224 && t < 240) { possum[t - 224] = 0.f; negsum[t - 224] = 0.f; }
    __syncthreads();
    for (int r = w; r < cnt; r += 4)
        ((uint2*)(srows8 + r * ROWU))[lane] = ((const uint2*)(embn8 + (size_t)wids[r] * 128))[lane];
    __syncthreads();

    const int mrow = lane & 15, q = lane >> 4;
    const int arow = (l0 - base) + mrow;     // LDS row of anchor #mrow
    const char* embc = (const char*)embn8;   // byte rows, stride 512
    const char* ap = (const char*)(srows8 + arow * ROWU) + q * 8;

    for (int job = w; job < 12; job += 4) {
        f32x4 acc0 = {0.f, 0.f, 0.f, 0.f};
        f32x4 acc1 = {0.f, 0.f, 0.f, 0.f};
        if (job < 10) {
            // ---- neg tile: cands c = 16*job .. +15, col = mrow ----
            const int c = job * 16 + mrow;
            const int node = snid[c];
            const char* bp = embc + (size_t)node * 512 + q * 8;
#pragma unroll
            for (int k0 = 0; k0 < 256; k0 += 32) {
                i64_t a0 = *(const i64_t*)(ap + k0);
                i64_t b0 = *(const i64_t*)(bp + k0);
                acc0 = __builtin_amdgcn_mfma_f32_16x16x32_fp8_fp8(a0, b0, acc0, 0, 0, 0);
                i64_t a1 = *(const i64_t*)(ap + k0 + 256);
                i64_t b1 = *(const i64_t*)(bp + k0 + 256);
                acc1 = __builtin_amdgcn_mfma_f32_16x16x32_fp8_fp8(a1, b1, acc1, 0, 0, 0);
            }
            const int owner = c / 10;
#pragma unroll
            for (int reg = 0; reg < 4; reg++) {
                const int a_local = q * 4 + reg;
                float e = 0.f;
                if (owner == a_local) {
                    const int l_a = l0 + a_local;
                    bool msk = false;
#pragma unroll
                    for (int dj = -WINDOW; dj <= WINDOW; dj++) {
                        if (dj == 0) continue;
                        int p = l_a + dj;
                        if (p >= 0 && p < WALK_LEN && wids[p - base] == node) msk = true;
                    }
                    if (!msk) e = __expf((acc0[reg] + acc1[reg]) * INV_TEMP);
                }
#pragma unroll
                for (int o = 1; o < 16; o <<= 1) e += __shfl_xor(e, o, 64);
                if (mrow == 0 && e != 0.f) atomicAdd(&negsum[a_local], e);
            }
        } else {
            // ---- pos tile: LDS rows r = 16*(job-10) .. +15 ----
            const int r = (job - 10) * 16 + mrow;
            const int rc = r < (cnt - 1) ? r : (cnt - 1);
            const char* bp = (const char*)(srows8 + rc * ROWU) + q * 8;
#pragma unroll
            for (int k0 = 0; k0 < 256; k0 += 32) {
                i64_t a0 = *(const i64_t*)(ap + k0);
                i64_t b0 = *(const i64_t*)(bp + k0);
                acc0 = __builtin_amdgcn_mfma_f32_16x16x32_fp8_fp8(a0, b0, acc0, 0, 0, 0);
                i64_t a1 = *(const i64_t*)(ap + k0 + 256);
                i64_t b1 = *(const i64_t*)(bp + k0 + 256);
                acc1 = __builtin_amdgcn_mfma_f32_16x16x32_fp8_fp8(a1, b1, acc1, 0, 0, 0);
            }
            const int pg = base + r;                 // walk position of this row
#pragma unroll
            for (int reg = 0; reg < 4; reg++) {
                const int a_local = q * 4 + reg;
                const int l_a = l0 + a_local;
                const int d = pg - l_a;
                bool use = (r < cnt) && (d != 0) && (d >= -WINDOW) && (d <= WINDOW);
                float e = use ? __expf((acc0[reg] + acc1[reg]) * INV_TEMP) : 0.f;
#pragma unroll
                for (int o = 1; o < 16; o <<= 1) e += __shfl_xor(e, o, 64);
                if (mrow == 0 && e != 0.f) atomicAdd(&possum[a_local], e);
            }
        }
    }
    __syncthreads();
    if (t < 16) {
        float term = logf(1.f + negsum[t] / possum[t]);   // possum > 0 always
#pragma unroll
        for (int o = 8; o > 0; o >>= 1) term += __shfl_xor(term, o, 64);
        if (t == 0) atomicAdd(out, term);
    }
}

extern "C" void kernel_launch(void* const* d_in, const int* in_sizes, int n_in,
                              void* d_out, int out_size, void* d_ws, size_t ws_size,
                              hipStream_t stream) {
    const float* x      = (const float*)d_in[0];
    const int*   ei     = (const int*)d_in[1];
    const int*   walks  = (const int*)d_in[2];
    const int*   negs   = (const int*)d_in[3];
    const float* W1     = (const float*)d_in[4];
    const float* a_src1 = (const float*)d_in[5];
    const float* a_dst1 = (const float*)d_in[6];
    const float* b1     = (const float*)d_in[7];
    const float* W2     = (const float*)d_in[8];
    const float* a_src2 = (const float*)d_in[9];
    const float* a_dst2 = (const float*)d_in[10];
    const float* b2     = (const float*)d_in[11];
    float* out = (float*)d_out;

    float* ws = (float*)d_ws;
    size_t off = 0;
    float* r_xw8   = ws + off; off += (size_t)N_NODES * 64;    // [N][256] fp8
    float* r_emb1b = ws + off; off += (size_t)N_NODES * 128;   // [N][256] bf16
    float* r_embn8 = ws + off; off += (size_t)N_NODES * 128;   // [N][512] fp8
    float* r_xb    = ws + off; off += (size_t)N_NODES * 64;    // [N][128] bf16
    float* r_wt1   = ws + off; off += 256 * 64;                // [256][128] bf16
    float* r_wt2   = ws + off; off += 256 * 128;               // [256][256] bf16
    float* als1  = ws + off; off += N_NODES * HEADS_1;
    float* ald1  = ws + off; off += N_NODES * HEADS_1;
    float* als2  = ws + off; off += N_NODES;
    float* ald2  = ws + off; off += N_NODES;
    int* deg       = (int*)(ws + off); off += N_NODES;
    int* excl      = (int*)(ws + off); off += N_NODES;
    int* bsum      = (int*)(ws + off); off += 256;
    int* row_start = (int*)(ws + off); off += N_NODES + 1;
    int* cursor    = (int*)(ws + off); off += N_NODES;
    int* srclist   = (int*)(ws + off); off += E_EDGES;
    uint*   xw8   = (uint*)r_xw8;
    ushort* emb1b = (ushort*)r_emb1b;
    uint*   embn8 = (uint*)r_embn8;
    ushort* xb    = (ushort*)r_xb;
    ushort* wt1   = (ushort*)r_wt1;
    ushort* wt2   = (ushort*)r_wt2;

    hipMemsetAsync(out, 0, sizeof(float) * out_size, stream);
    hipMemsetAsync(deg, 0, sizeof(int) * N_NODES, stream);
    hipMemsetAsync(cursor, 0, sizeof(int) * N_NODES, stream);

    // ---- CSR build (shared by both layers) ----
    deg_kernel<<<(E_EDGES + 255) / 256, 256, 0, stream>>>(ei, deg);
    scan_a<<<SCAN_BLOCKS, 256, 0, stream>>>(deg, excl, bsum);
    scan_b<<<1, 256, 0, stream>>>(bsum);
    scan_c2<<<SCAN_BLOCKS, 256, 0, stream>>>(excl, bsum, row_start);
    bucket_kernel<<<(E_EDGES + 255) / 256, 256, 0, stream>>>(ei, row_start, cursor, srclist);

    // ---- bf16 conversions ----
    f32_to_bf16_kernel<<<(N_NODES * FDIM_IN / 4 + 255) / 256, 256, 0, stream>>>(
        x, (uint*)xb, N_NODES * FDIM_IN / 4);
    wtrans_kernel<<<(256 * 128 + 255) / 256, 256, 0, stream>>>(W1, wt1, 128);
    wtrans_kernel<<<(256 * 256 + 255) / 256, 256, 0, stream>>>(W2, wt2, 256);

    // ---- layer 1 (heads=8, hid=32) ----
    mfma_gemm<128><<<N_NODES / 16, 256, 0, stream>>>(xb, wt1, xw8);
    al_wave_kernel<HEADS_1><<<(N_NODES * 64 + 255) / 256, 256, 0, stream>>>(
        xw8, a_src1, a_dst1, als1, ald1);
    gat_gather1<<<N_NODES / 4, 256, 0, stream>>>(
        row_start, srclist, als1, ald1, xw8, b1, emb1b);

    // ---- layer 2 (heads=1, hid=256), fused normalize + fp8 pack ----
    mfma_gemm<256><<<N_NODES / 16, 256, 0, stream>>>(emb1b, wt2, xw8);
    al_wave_kernel<1><<<(N_NODES * 64 + 255) / 256, 256, 0, stream>>>(
        xw8, a_src2, a_dst2, als2, ald2);
    gat_gather2<<<N_NODES / 4, 256, 0, stream>>>(
        row_start, srclist, als2, ald2, xw8, b2, emb1b, embn8);

    // ---- contrastive loss (fp8 MFMA) ----
    loss_mfma_kernel<<<NUM_WALKS * 4, 256, 0, stream>>>(embn8, walks, negs, out);
}